// Round 7
// baseline (1072.065 us; speedup 1.0000x reference)
//
#include <hip/hip_runtime.h>
#include <hip/hip_cooperative_groups.h>

// GraphAttentionEmbedding: 2x TransformerConv (PyG) on MI355X (gfx950).
// N=50000, E=400000, IN=128, H1=8*16=128, OUT=128, EDIM=32.
// PROVEN: fp32 inputs (runtime-detected), fp32 output; internal bf16+fp32 acc.
// R17-R20 lessons: attn pinned at ~59us across occ 30-49% and MLP 24-48
// loads/wave -> leave attn at R18's proven form (1 node/wave, exact-8+masked-4).
// Non-attn ~310us vs ~120us of hand-computed work -> ~190us is launch/drain
// overhead across 14 serialized dispatches.
// R21: ONE cooperative kernel for all prep (zero-deg, convert x, count deg,
// weight transpose+wqe+WeP, 3-phase scan, fill_csr, gather_ef) with
// grid.sync() barriers; dispatches 14 -> 5. Fallback to multi-launch path if
// cooperative launch fails.

namespace cg = cooperative_groups;

using u16 = unsigned short;
using u32 = unsigned int;

#define NODES 50000
#define EDGES 400000
#define NB196 196   // ceil(50000/256)
#define COOPG 512   // cooperative grid: 2 blocks/CU, trivially co-resident

typedef __attribute__((ext_vector_type(8))) short bf16x8;
typedef __attribute__((ext_vector_type(4))) float f32x4;

__device__ __forceinline__ float bflo(u32 u) { return __uint_as_float(u << 16); }
__device__ __forceinline__ float bfhi(u32 u) { return __uint_as_float(u & 0xffff0000u); }
__device__ __forceinline__ u16 f2bf(float f) {
    u32 u = __float_as_uint(f);
    u += 0x7fffu + ((u >> 16) & 1u);   // RNE
    return (u16)(u >> 16);
}
__device__ __forceinline__ u32 pack2(float a, float b) {
    return (u32)f2bf(a) | ((u32)f2bf(b) << 16);
}
__device__ __forceinline__ float rdv(const void* p, int i, int f) {
    return f ? ((const float*)p)[i]
             : __uint_as_float(((u32) reinterpret_cast<const u16*>(p)[i]) << 16);
}

// dot2 on packed bf16 pairs: p = a.lo*b.lo + a.hi*b.hi + c
#if __has_builtin(__builtin_amdgcn_fdot2_f32_bf16)
typedef __attribute__((ext_vector_type(2))) __bf16 bf2;
__device__ __forceinline__ float dot2bf(u32 a, u32 b, float c) {
    return __builtin_amdgcn_fdot2_f32_bf16(__builtin_bit_cast(bf2, a),
                                           __builtin_bit_cast(bf2, b), c, false);
}
#else
__device__ __forceinline__ float dot2bf(u32 a, u32 b, float c) {
    return fmaf(bflo(a), bflo(b), fmaf(bfhi(a), bfhi(b), c));
}
#endif

__device__ __forceinline__ float fexp2(float x) {
#if __has_builtin(__builtin_amdgcn_exp2f)
    return __builtin_amdgcn_exp2f(x);
#else
    return exp2f(x);
#endif
}

// DPP lane-add at VALU speed (no DS pipe).
template <int CTRL>
__device__ __forceinline__ float dpp_addf(float x) {
    int y = __builtin_amdgcn_update_dpp(0, __float_as_int(x), CTRL, 0xF, 0xF, true);
    return x + __int_as_float(y);
}
template <int GRP>
__device__ __forceinline__ float grp_sum(float p, int lane) {
    p = dpp_addf<0xB1>(p);    // xor 1
    p = dpp_addf<0x4E>(p);    // xor 2
    p = dpp_addf<0x141>(p);   // xor 4 (8-group done)
    if (GRP == 64) {
        p = dpp_addf<0x140>(p);   // xor 8
        p += __int_as_float(__builtin_amdgcn_ds_swizzle(__float_as_int(p), 0x401F)); // xor16
        p += __int_as_float(__builtin_amdgcn_ds_bpermute((lane ^ 32) << 2,
                                                         __float_as_int(p)));        // xor32
    }
    return p;
}

// Broadcast lane ((lane&0x18)|SRC)'s u32 to its 8-lane group (BitMode swizzle).
template <int SRC>
__device__ __forceinline__ u32 bcast8u(u32 x) {
    return (u32)__builtin_amdgcn_ds_swizzle((int)x, 0x18 | (SRC << 5));
}

// ---------------- diagnostic sentinel (fp32 out) ----------------------------
__global__ __launch_bounds__(256) void fill_sentinel(float* __restrict__ out, int n, float val) {
    int i = blockIdx.x * 256 + threadIdx.x;
    if (i < n) out[i] = val;
}

// ---------------- shared structs --------------------------------------------
struct TPtrs {
    const void* src[8];
    u16*        dst[8];
    int         K[8];
};
struct WqeP {
    const void *Wq1, *We1, *bq1, *Wq2, *We2, *bq2;
    u16 *WtA, *WtB, *Wt2;
    float *bqe1, *bqe2;
    uint2 *WeP1, *WeP2;
};

// ---------------- wqe item (shared between coop + fallback) -----------------
// L1: Wqe1[i, h*32+d] = sum_{c<16} Wq1[i,16h+c]*We1[d,16h+c] -> WtA/WtB.
// L2: Wqe2[i, d] = 0.125 * sum_{c<128} Wq2[i,c]*We2[d,c] (d<32; rest 0).
// biases bqe1[256], bqe2[128] (fp32, bqe2 x0.125). WeP packed along d.
__device__ __forceinline__ void wqe_item(const WqeP& Q, int idx, int f) {
    if (idx < 32768) {                          // layer-1 combined weights
        int col = idx >> 7, i = idx & 127;
        int hh = col >> 5, d = col & 31;
        float s = 0.f;
#pragma unroll
        for (int c = 0; c < 16; ++c)
            s += rdv(Q.Wq1, i * 128 + hh * 16 + c, f) * rdv(Q.We1, d * 128 + hh * 16 + c, f);
        if (col < 128) Q.WtA[col * 128 + i] = f2bf(s);
        else           Q.WtB[(col - 128) * 128 + i] = f2bf(s);
    } else if (idx < 49152) {                   // layer-2 weights (zero-padded, x0.125)
        int t = idx - 32768;
        int col = t >> 7, i = t & 127;
        float s = 0.f;
        if (col < 32) {
            for (int c = 0; c < 128; ++c)
                s += rdv(Q.Wq2, i * 128 + c, f) * rdv(Q.We2, col * 128 + c, f);
        }
        Q.Wt2[col * 128 + i] = f2bf(s * 0.125f);
    } else if (idx < 49408) {                   // bqe1
        int col = idx - 49152;
        int hh = col >> 5, d = col & 31;
        float s = 0.f;
#pragma unroll
        for (int c = 0; c < 16; ++c)
            s += rdv(Q.bq1, hh * 16 + c, f) * rdv(Q.We1, d * 128 + hh * 16 + c, f);
        Q.bqe1[col] = s;
    } else if (idx < 49536) {                   // bqe2 (x0.125)
        int d = idx - 49408;
        float s = 0.f;
        if (d < 32)
            for (int c = 0; c < 128; ++c)
                s += rdv(Q.bq2, c, f) * rdv(Q.We2, d * 128 + c, f);
        Q.bqe2[d] = s * 0.125f;
    } else if (idx < 50560) {                   // WeP1: 1024 entries
        int ent = idx - 49536;
        int t = ent >> 6, l = ent & 63, c0 = 2 * l;
        u32 xv = pack2(rdv(Q.We1, (2 * t) * 128 + c0, f),
                       rdv(Q.We1, (2 * t + 1) * 128 + c0, f));
        u32 yv = pack2(rdv(Q.We1, (2 * t) * 128 + c0 + 1, f),
                       rdv(Q.We1, (2 * t + 1) * 128 + c0 + 1, f));
        Q.WeP1[ent] = make_uint2(xv, yv);
    } else if (idx < 51584) {                   // WeP2: 1024 entries
        int ent = idx - 50560;
        int t = ent >> 6, l = ent & 63, c0 = 2 * l;
        u32 xv = pack2(rdv(Q.We2, (2 * t) * 128 + c0, f),
                       rdv(Q.We2, (2 * t + 1) * 128 + c0, f));
        u32 yv = pack2(rdv(Q.We2, (2 * t) * 128 + c0 + 1, f),
                       rdv(Q.We2, (2 * t + 1) * 128 + c0 + 1, f));
        Q.WeP2[ent] = make_uint2(xv, yv);
    }
}

__device__ __forceinline__ int block_scan256(int v) {
    __shared__ int ws[4];
    int t = threadIdx.x, lane = t & 63, w = t >> 6;
    int x = v;
#pragma unroll
    for (int off = 1; off < 64; off <<= 1) {
        int y = __shfl_up(x, off, 64);
        if (lane >= off) x += y;
    }
    if (lane == 63) ws[w] = x;
    __syncthreads();
#pragma unroll
    for (int j = 0; j < 3; ++j)
        if (j < w) x += ws[j];
    return x;
}

// ---------------- ONE cooperative prep kernel (replaces 9 dispatches) -------
struct CoopArgs {
    const void* X;
    const int*  raw;
    const void* EF;
    TPtrs tp;
    WqeP  wq;
    int* flags;
    int* deg; int* bsum; int* row_ptr; int* cursor;
    int* srcs; int* eids;
    u16* xbf; u16* efg;
};

__global__ __launch_bounds__(256) void coop_prep(CoopArgs A) {
    cg::grid_group grid = cg::this_grid();
    const int gid = blockIdx.x * 256 + threadIdx.x;
    const int gsz = gridDim.x * 256;
    const int lane = threadIdx.x & 63;
    const int N = NODES, E = EDGES;

    // inline per-wave format detection (L2-hot after first wave)
    u32 ew = (((const u32*)A.X)[lane] >> 7) & 0xffu;
    unsigned long long sane = __ballot(ew >= 90u && ew <= 141u);
    unsigned long long zodd = __ballot(A.raw[1 + 2 * lane] == 0);
    const int f  = (sane == ~0ull) ? 0 : 1;   // 1 = fp32
    const int f1 = (zodd == ~0ull) ? 1 : 0;   // 1 = int64
    if (gid == 0) { A.flags[0] = f; A.flags[1] = f1; }

    // phase A: zero deg
    for (int i = gid; i < N; i += gsz) A.deg[i] = 0;
    __threadfence();
    grid.sync();

    // phase B: convert x -> bf16; count deg; transpose weights; wqe/WeP
    for (int i = gid; i < N * 128 / 8; i += gsz) {
        int o = i * 8;
        if (f) {
            const float* xf = (const float*)A.X + o;
            float4 lo = *reinterpret_cast<const float4*>(xf);
            float4 hi = *reinterpret_cast<const float4*>(xf + 4);
            *reinterpret_cast<uint4*>(A.xbf + o) =
                make_uint4(pack2(lo.x, lo.y), pack2(lo.z, lo.w),
                           pack2(hi.x, hi.y), pack2(hi.z, hi.w));
        } else {
            *reinterpret_cast<uint4*>(A.xbf + o) =
                *reinterpret_cast<const uint4*>((const u16*)A.X + o);
        }
    }
    for (int e = gid; e < E; e += gsz) {
        int d = f1 ? A.raw[2 * (E + e)] : A.raw[E + e];
        if ((unsigned)d < (unsigned)N) atomicAdd(&A.deg[d], 1);
    }
    for (int t = gid; t < 8 * 16384; t += gsz) {
        int m = t >> 14, idx = t & 16383;
        int k = idx >> 7, n = idx & 127;
        const float* sf = (const float*)A.tp.src[m];
        const u16*   sb = (const u16*)A.tp.src[m];
        A.tp.dst[m][n * 128 + k] = f ? f2bf(sf[idx]) : sb[idx];
    }
    for (int idx = gid; idx < 51584; idx += gsz) wqe_item(A.wq, idx, f);
    __threadfence();
    grid.sync();

    // phase C: per-chunk inclusive scan -> bsum
    for (int c = blockIdx.x; c < NB196; c += gridDim.x) {
        int i = c * 256 + threadIdx.x;
        int v = (i < N) ? A.deg[i] : 0;
        int incl = block_scan256(v);
        if (threadIdx.x == 255) A.bsum[c] = incl;
    }
    __threadfence();
    grid.sync();

    // phase D: block 0 scans bsum (196 <= 256)
    if (blockIdx.x == 0) {
        int t = threadIdx.x;
        int v = (t < NB196) ? A.bsum[t] : 0;
        int incl = block_scan256(v);
        if (t < NB196) A.bsum[t] = incl - v;
    }
    __threadfence();
    grid.sync();

    // phase E: row_ptr + cursor
    for (int c = blockIdx.x; c < NB196; c += gridDim.x) {
        int i = c * 256 + threadIdx.x;
        int v = (i < N) ? A.deg[i] : 0;
        int incl = block_scan256(v) + A.bsum[c];
        if (i < N) { A.row_ptr[i + 1] = incl; A.cursor[i] = incl - v; }
        if (i == 0) A.row_ptr[0] = 0;
    }
    __threadfence();
    grid.sync();

    // phase F: fill CSR
    for (int e = gid; e < E; e += gsz) {
        int d = f1 ? A.raw[2 * (E + e)] : A.raw[E + e];
        int s = f1 ? A.raw[2 * e] : A.raw[e];
        if ((unsigned)d < (unsigned)N && (unsigned)s < (unsigned)N) {
            int pos = atomicAdd(&A.cursor[d], 1);
            if ((unsigned)pos < (unsigned)E) { A.srcs[pos] = s; A.eids[pos] = e; }
        }
    }
    __threadfence();
    grid.sync();

    // phase G: gather ef -> efg (CSR order, bf16; shared by both layers)
    for (int t = gid; t < E * 4; t += gsz) {
        int pos = t >> 2, seg = t & 3;
        int e = A.eids[pos];
        uint4 val;
        if (f) {
            const float* src = (const float*)A.EF + (size_t)e * 32 + seg * 8;
            float4 lo = *reinterpret_cast<const float4*>(src);
            float4 hi = *reinterpret_cast<const float4*>(src + 4);
            val = make_uint4(pack2(lo.x, lo.y), pack2(lo.z, lo.w),
                             pack2(hi.x, hi.y), pack2(hi.z, hi.w));
        } else {
            val = *reinterpret_cast<const uint4*>((const u16*)A.EF + (size_t)e * 32 + seg * 8);
        }
        *reinterpret_cast<uint4*>(A.efg + (size_t)pos * 32 + seg * 8) = val;
    }
}

// ---------------- fallback multi-launch prep kernels ------------------------
__global__ __launch_bounds__(64) void detect_fmt(const u32* __restrict__ xw,
                                                 const int* __restrict__ eraw,
                                                 int* __restrict__ flags) {
    int lane = threadIdx.x;
    u32 e = (xw[lane] >> 7) & 0xffu;
    unsigned long long sane = __ballot(e >= 90u && e <= 141u);
    unsigned long long zodd = __ballot(eraw[1 + 2 * lane] == 0);
    if (lane == 0) {
        flags[0] = (sane == ~0ull) ? 0 : 1;
        flags[1] = (zodd == ~0ull) ? 1 : 0;
    }
}

#define CXB 3125    // 50000*128/8/256
#define CDB 1563    // ceil(400000/256)
__global__ __launch_bounds__(256) void convert_count(
    const void* __restrict__ X, const int* __restrict__ raw,
    const int* __restrict__ flags, u16* __restrict__ xbf,
    int* __restrict__ deg, int total, int E) {
    int b = blockIdx.x;
    if (b < CXB) {
        int i = (b * 256 + threadIdx.x) * 8;
        if (i >= total) return;
        if (flags[0]) {
            const float* xf = (const float*)X + i;
            float4 lo = *reinterpret_cast<const float4*>(xf);
            float4 hi = *reinterpret_cast<const float4*>(xf + 4);
            uint4 val = make_uint4(pack2(lo.x, lo.y), pack2(lo.z, lo.w),
                                   pack2(hi.x, hi.y), pack2(hi.z, hi.w));
            *reinterpret_cast<uint4*>(xbf + i) = val;
        } else {
            *reinterpret_cast<uint4*>(xbf + i) =
                *reinterpret_cast<const uint4*>((const u16*)X + i);
        }
    } else {
        int e = (b - CXB) * 256 + threadIdx.x;
        if (e < E) {
            int f = flags[1];
            int d = f ? raw[2 * (E + e)] : raw[E + e];
            if ((unsigned)d < (unsigned)NODES) atomicAdd(&deg[d], 1);
        }
    }
}

__global__ __launch_bounds__(256) void prep_w(TPtrs P, WqeP Q, const int* __restrict__ flags) {
    int f = flags[0];
    int b = blockIdx.x;
    if (b < 32) {
        int m = b >> 2;
        int quarter = 16384 >> 2;
        u16* d = P.dst[m];
        int base = (b & 3) * quarter;
        const float* sf = (const float*)P.src[m];
        const u16*   sb = (const u16*)P.src[m];
        for (int idx = base + threadIdx.x; idx < base + quarter; idx += 256) {
            int k = idx >> 7, n = idx & 127;
            d[n * 128 + k] = f ? f2bf(sf[idx]) : sb[idx];
        }
        return;
    }
    int idx = (b - 32) * 256 + threadIdx.x;
    if (idx < 51584) wqe_item(Q, idx, f);
}

__global__ __launch_bounds__(256) void scan_a(const int* __restrict__ deg,
                                              int* __restrict__ bsum, int n) {
    int i = blockIdx.x * 256 + threadIdx.x;
    int v = (i < n) ? deg[i] : 0;
    int incl = block_scan256(v);
    if (threadIdx.x == 255) bsum[blockIdx.x] = incl;
}

__global__ __launch_bounds__(256) void scan_b(int* __restrict__ bsum, int nb) {
    int t = threadIdx.x;
    int v = (t < nb) ? bsum[t] : 0;
    int incl = block_scan256(v);
    if (t < nb) bsum[t] = incl - v;
}

__global__ __launch_bounds__(256) void scan_c(const int* __restrict__ deg,
                                              const int* __restrict__ bsum,
                                              int* __restrict__ row_ptr,
                                              int* __restrict__ cursor, int n) {
    int b = blockIdx.x;
    int i = b * 256 + threadIdx.x;
    int v = (i < n) ? deg[i] : 0;
    int incl = block_scan256(v) + bsum[b];
    if (i < n) {
        row_ptr[i + 1] = incl;
        cursor[i] = incl - v;
    }
    if (i == 0) row_ptr[0] = 0;
}

__global__ __launch_bounds__(256) void fill_csr(const int* __restrict__ raw,
                                                const int* __restrict__ flags,
                                                int* __restrict__ cursor,
                                                int* __restrict__ srcs,
                                                int* __restrict__ eids, int E) {
    int e = blockIdx.x * 256 + threadIdx.x;
    if (e < E) {
        int f = flags[1];
        int d = f ? raw[2 * (E + e)] : raw[E + e];
        int s = f ? raw[2 * e] : raw[e];
        if ((unsigned)d < (unsigned)NODES && (unsigned)s < (unsigned)NODES) {
            int pos = atomicAdd(&cursor[d], 1);
            if ((unsigned)pos < (unsigned)E) { srcs[pos] = s; eids[pos] = e; }
        }
    }
}

__global__ __launch_bounds__(256) void gather_ef(const int* __restrict__ eids,
                                                 const void* __restrict__ EF,
                                                 const int* __restrict__ flags,
                                                 u16* __restrict__ EFG, int E) {
    int t = blockIdx.x * 256 + threadIdx.x;
    int pos = t >> 2, seg = t & 3;
    if (pos >= E) return;
    int e = eids[pos];
    uint4 val;
    if (flags[0]) {
        const float* src = (const float*)EF + (size_t)e * 32 + seg * 8;
        float4 lo = *reinterpret_cast<const float4*>(src);
        float4 hi = *reinterpret_cast<const float4*>(src + 4);
        val = make_uint4(pack2(lo.x, lo.y), pack2(lo.z, lo.w),
                         pack2(hi.x, hi.y), pack2(hi.z, hi.w));
    } else {
        val = *reinterpret_cast<const uint4*>((const u16*)EF + (size_t)e * 32 + seg * 8);
    }
    *reinterpret_cast<uint4*>(EFG + (size_t)pos * 32 + seg * 8) = val;
}

// ---------------- GEMM: O[M,128] = (A[M,128] @ Wt^T + bias) * oscale --------
struct GemmSets {
    const u16*  Wt[6];
    const void* bias[6];
    u16*        O[6];
    int         bf32[6];    // 1 = bias is fp32 always, 0 = follow input flags
    int         pitch[6];   // output row pitch in u16 elements
    float       oscale[6];  // output scale (1.0 for k/v/sk)
};

__global__ __launch_bounds__(256) void gemm128(
    const u16* __restrict__ A, const int* __restrict__ flags, GemmSets S, int M) {
    constexpr int K = 128;
    constexpr int PAD = K + 8;
    constexpr int KV = K / 8;
    __shared__ u16 Asl[64 * PAD];
    __shared__ u16 Bsl[128 * PAD];

    const u16*  Wt   = S.Wt[blockIdx.y];
    const void* bias = S.bias[blockIdx.y];
    u16*        O    = S.O[blockIdx.y];
    int pitch = S.pitch[blockIdx.y];
    float os  = S.oscale[blockIdx.y];
    int f = S.bf32[blockIdx.y] ? 1 : flags[0];
    int m0 = blockIdx.x * 64;

    for (int idx = threadIdx.x; idx < 64 * KV; idx += 256) {
        int r = idx / KV, cv = idx % KV;
        int gr = m0 + r;
        uint4 val = make_uint4(0, 0, 0, 0);
        if (gr < M) val = *reinterpret_cast<const uint4*>(A + (size_t)gr * K + cv * 8);
        *reinterpret_cast<uint4*>(&Asl[r * PAD + cv * 8]) = val;
    }
    for (int idx = threadIdx.x; idx < 128 * KV; idx += 256) {
        int r = idx / KV, cv = idx % KV;
        *reinterpret_cast<uint4*>(&Bsl[r * PAD + cv * 8]) =
            *reinterpret_cast<const uint4*>(Wt + r * K + cv * 8);
    }
    __syncthreads();

    int lane = threadIdx.x & 63, wv = threadIdx.x >> 6;
    int l15 = lane & 15;
    int quad = lane >> 4;
    int kq = quad * 8;

    f32x4 b4[8];
#pragma unroll
    for (int nt = 0; nt < 8; ++nt) {
        int col0 = nt * 16 + quad * 4;
        if (bias) {
            if (f) {
                b4[nt] = *reinterpret_cast<const f32x4*>((const float*)bias + col0);
            } else {
                uint2 bu = *reinterpret_cast<const uint2*>((const u16*)bias + col0);
                b4[nt][0] = bflo(bu.x); b4[nt][1] = bfhi(bu.x);
                b4[nt][2] = bflo(bu.y); b4[nt][3] = bfhi(bu.y);
            }
        } else {
            b4[nt][0] = b4[nt][1] = b4[nt][2] = b4[nt][3] = 0.f;
        }
    }

    f32x4 acc[8] = {};
#pragma unroll
    for (int k0 = 0; k0 < K; k0 += 32) {
        bf16x8 xf = *reinterpret_cast<const bf16x8*>(&Asl[(wv * 16 + l15) * PAD + k0 + kq]);
#pragma unroll
        for (int nt = 0; nt < 8; ++nt) {
            bf16x8 wf = *reinterpret_cast<const bf16x8*>(&Bsl[(nt * 16 + l15) * PAD + k0 + kq]);
            acc[nt] = __builtin_amdgcn_mfma_f32_16x16x32_bf16(wf, xf, acc[nt], 0, 0, 0);
        }
    }

    int row = m0 + wv * 16 + l15;
    if (row < M) {
        u16* Orow = O + (size_t)row * pitch;
#pragma unroll
        for (int nt = 0; nt < 8; ++nt) {
            uint2 pk;
            pk.x = pack2((acc[nt][0] + b4[nt][0]) * os, (acc[nt][1] + b4[nt][1]) * os);
            pk.y = pack2((acc[nt][2] + b4[nt][2]) * os, (acc[nt][3] + b4[nt][3]) * os);
            *reinterpret_cast<uint2*>(Orow + nt * 16 + quad * 4) = pk;
        }
    }
}

// ---------------- attention: R18 proven form (59.4us, VGPR 40) --------------
// Per wave = one dst node. Lane (h=lane>>3, j=lane&7) owns channels 16h+2j..+1
// and ef dims 4j..4j+3. Score p = q.k + qw.ef (scale pre-folded via gemm
// oscale) -> w = exp2(p). Exact-8 main loop + masked-4 tail. Epilogue: F
// packed bf16, bcast8 per group, dot2 vs WeP (loaded post-loop).
template <int HEADS, int F32OUT>
__global__ __launch_bounds__(256) void attn_kernel(
    const int* __restrict__ row_ptr, const int* __restrict__ srcs,
    const u16* __restrict__ Q, const u16* __restrict__ KV,
    const u16* __restrict__ EFG,
    const u16* __restrict__ QWA, const u16* __restrict__ QWB,
    const u16* __restrict__ SK, const uint2* __restrict__ WeP,
    void* __restrict__ OUT, int nn) {
    int wv = threadIdx.x >> 6, lane = threadIdx.x & 63;
    int node = blockIdx.x * 4 + wv;
    if (node >= nn) return;
    int h = lane >> 3, j = lane & 7;
    int c0 = lane * 2;
    constexpr int GRP = (HEADS == 8) ? 8 : 64;

    u32 qb = *reinterpret_cast<const u32*>(Q + (size_t)node * 128 + c0);
    const u16* qp = (HEADS == 8)
        ? ((h < 4 ? QWA : QWB) + (size_t)node * 128 + (h & 3) * 32 + j * 4)
        : (QWA + (size_t)node * 128 + j * 4);
    uint2 qwu = *reinterpret_cast<const uint2*>(qp);

    int beg = __builtin_amdgcn_readfirstlane(row_ptr[node]);
    int end = __builtin_amdgcn_readfirstlane(row_ptr[node + 1]);

    float l_run = 0.f, a0 = 0.f, a1 = 0.f;
    float f0 = 0.f, f1 = 0.f, f2 = 0.f, f3 = 0.f;

    auto edge_step = [&](u32 kbv, u32 vbv, uint2 ebv, bool valid) {
        float p = dot2bf(qb, kbv,
                 dot2bf(qwu.x, ebv.x,
                 dot2bf(qwu.y, ebv.y, 0.f)));
        p = grp_sum<GRP>(p, lane);
        float w = fexp2(p);
        if (!valid) w = 0.f;
        l_run += w;
        a0 = fmaf(w, bflo(vbv), a0);
        a1 = fmaf(w, bfhi(vbv), a1);
        f0 = fmaf(w, bflo(ebv.x), f0); f1 = fmaf(w, bfhi(ebv.x), f1);
        f2 = fmaf(w, bflo(ebv.y), f2); f3 = fmaf(w, bfhi(ebv.y), f3);
    };

    int i = beg;
    for (; i + 8 <= end; i += 8) {          // exact batches, no masking
        u32 kb[8], vb[8]; uint2 eb[8];
#pragma unroll
        for (int t = 0; t < 8; ++t) {
            int s = srcs[i + t];            // uniform -> s_load
            const u16* kp = KV + (size_t)s * 256;
            kb[t] = *reinterpret_cast<const u32*>(kp + c0);
            vb[t] = *reinterpret_cast<const u32*>(kp + 128 + c0);
            eb[t] = *reinterpret_cast<const uint2*>(EFG + (size_t)(i + t) * 32 + j * 4);
        }
#pragma unroll
        for (int t = 0; t < 8; ++t) edge_step(kb[t], vb[t], eb[t], true);
    }
    for (; i < end; i += 4) {               // masked tail, batch 4
        int kleft = end - i;
        u32 kb[4], vb[4]; uint2 eb[4];
#pragma unroll
        for (int t = 0; t < 4; ++t) {
            int idx = (i + t < end) ? i + t : end - 1;
            int s = srcs[idx];
            const u16* kp = KV + (size_t)s * 256;
            kb[t] = *reinterpret_cast<const u32*>(kp + c0);
            vb[t] = *reinterpret_cast<const u32*>(kp + 128 + c0);
            eb[t] = *reinterpret_cast<const uint2*>(EFG + (size_t)idx * 32 + j * 4);
        }
#pragma unroll
        for (int t = 0; t < 4; ++t) edge_step(kb[t], vb[t], eb[t], t < kleft);
    }

    // ---- epilogue: out_ee[c] = sum_d F[d]*We[d][c], packed F + dot2 --------
    u32 Fp0 = pack2(f0, f1), Fp1 = pack2(f2, f3);
    float acc0 = 0.f, acc1 = 0.f;
#define EPI(SRC) do { \
        u32 A = bcast8u<SRC>(Fp0), B = bcast8u<SRC>(Fp1); \
        uint2 w0 = WeP[(2 * SRC) * 64 + lane]; \
        uint2 w1 = WeP[(2 * SRC + 1) * 64 + lane]; \
        acc0 = dot2bf(A, w0.x, acc0); acc0 = dot2bf(B, w1.x, acc0); \
        acc1 = dot2bf(A, w0.y, acc1); acc1 = dot2bf(B, w1.y, acc1); \
    } while (0)
    EPI(0); EPI(1); EPI(2); EPI(3); EPI(4); EPI(5); EPI(6); EPI(7);
#undef EPI

    float inv = 1.f / fmaxf(l_run, 1e-16f);
    u32 sb = *reinterpret_cast<const u32*>(SK + (size_t)node * 128 + c0);
    float o0 = fmaxf(fmaf(a0 + acc0, inv, bflo(sb)), 0.f);
    float o1 = fmaxf(fmaf(a1 + acc1, inv, bfhi(sb)), 0.f);
    if (F32OUT) {
        *reinterpret_cast<float2*>((float*)OUT + (size_t)node * 128 + c0) =
            make_float2(o0, o1);
    } else {
        *reinterpret_cast<u32*>((u16*)OUT + (size_t)node * 128 + c0) = pack2(o0, o1);
    }
}

// ---------------------------------------------------------------------------
extern "C" void kernel_launch(void* const* d_in, const int* in_sizes, int n_in,
                              void* d_out, int out_size, void* d_ws, size_t ws_size,
                              hipStream_t stream) {
    const int N = NODES, E = EDGES;
    const void* x  = d_in[0];
    const int*  ei = (const int*)d_in[1];
    const void* ef = d_in[2];
    const void* Wq1 = d_in[3];  const void* bq1 = d_in[4];
    const void* Wk1 = d_in[5];  const void* bk1 = d_in[6];
    const void* Wv1 = d_in[7];  const void* bv1 = d_in[8];
    const void* We1 = d_in[9];
    const void* Ws1 = d_in[10]; const void* bs1 = d_in[11];
    const void* Wq2 = d_in[12]; const void* bq2 = d_in[13];
    const void* Wk2 = d_in[14]; const void* bk2 = d_in[15];
    const void* Wv2 = d_in[16]; const void* bv2 = d_in[17];
    const void* We2 = d_in[18];
    const void* Ws2 = d_in[19]; const void* bs2 = d_in[20];

    char* ws = (char*)d_ws;
    size_t off = 0;
    auto carve = [&](size_t bytes) -> void* {
        void* p = ws + off;
        off += (bytes + 255) & ~(size_t)255;
        return p;
    };

    u16* WtQ1 = (u16*)carve(128 * 128 * 2);
    u16* WtK1 = (u16*)carve(128 * 128 * 2);
    u16* WtV1 = (u16*)carve(128 * 128 * 2);
    u16* WtS1 = (u16*)carve(128 * 128 * 2);
    u16* WtQ2 = (u16*)carve(128 * 128 * 2);
    u16* WtK2 = (u16*)carve(128 * 128 * 2);
    u16* WtV2 = (u16*)carve(128 * 128 * 2);
    u16* WtS2 = (u16*)carve(128 * 128 * 2);
    u16* WtqA = (u16*)carve(128 * 128 * 2);
    u16* WtqB = (u16*)carve(128 * 128 * 2);
    u16* Wtq2 = (u16*)carve(128 * 128 * 2);
    float* bqe1 = (float*)carve(256 * 4);
    float* bqe2 = (float*)carve(128 * 4);
    uint2* WeP1 = (uint2*)carve(1024 * 8);
    uint2* WeP2 = (uint2*)carve(1024 * 8);
    int* flags   = (int*)carve(256);
    int* deg     = (int*)carve((size_t)N * 4);
    int* bsum    = (int*)carve((size_t)NB196 * 4);
    int* row_ptr = (int*)carve((size_t)(N + 1) * 4);
    int* cursor  = (int*)carve((size_t)N * 4);
    int* srcs    = (int*)carve((size_t)E * 4);
    int* eids    = (int*)carve((size_t)E * 4);
    u16* xbf  = (u16*)carve((size_t)N * 128 * 2);
    u16* q    = (u16*)carve((size_t)N * 128 * 2);
    u16* kv   = (u16*)carve((size_t)N * 256 * 2);   // k rows [0:128], v rows [128:256]
    u16* sk   = (u16*)carve((size_t)N * 128 * 2);
    u16* h    = (u16*)carve((size_t)N * 128 * 2);
    u16* qweA = (u16*)carve((size_t)N * 128 * 2);
    u16* qweB = (u16*)carve((size_t)N * 128 * 2);
    u16* qwe2 = (u16*)carve((size_t)N * 128 * 2);
    u16* efg  = (u16*)carve((size_t)E * 32 * 2);
    const size_t REQ = off;   // ~146 MB

    if (ws_size < REQ) {
        hipLaunchKernelGGL(fill_sentinel, dim3((out_size + 255) / 256), dim3(256), 0, stream,
                           (float*)d_out, out_size, 16.0f * (float)(ws_size >> 20));
        return;
    }

    const float s2_1 = 0.25f * 1.44269504f;               // 1/sqrt(16) * log2(e)
    const float s2_2 = 0.08838834764831845f * 1.44269504f; // 1/sqrt(128) * log2(e)

    TPtrs tp;
    tp.src[0] = Wq1; tp.dst[0] = WtQ1; tp.K[0] = 128;
    tp.src[1] = Wk1; tp.dst[1] = WtK1; tp.K[1] = 128;
    tp.src[2] = Wv1; tp.dst[2] = WtV1; tp.K[2] = 128;
    tp.src[3] = Ws1; tp.dst[3] = WtS1; tp.K[3] = 128;
    tp.src[4] = Wq2; tp.dst[4] = WtQ2; tp.K[4] = 128;
    tp.src[5] = Wk2; tp.dst[5] = WtK2; tp.K[5] = 128;
    tp.src[6] = Wv2; tp.dst[6] = WtV2; tp.K[6] = 128;
    tp.src[7] = Ws2; tp.dst[7] = WtS2; tp.K[7] = 128;
    WqeP wp;
    wp.Wq1 = Wq1; wp.We1 = We1; wp.bq1 = bq1;
    wp.Wq2 = Wq2; wp.We2 = We2; wp.bq2 = bq2;
    wp.WtA = WtqA; wp.WtB = WtqB; wp.Wt2 = Wtq2;
    wp.bqe1 = bqe1; wp.bqe2 = bqe2;
    wp.WeP1 = WeP1; wp.WeP2 = WeP2;

    // ---- prep: ONE cooperative kernel (fallback: multi-launch path) --------
    CoopArgs ca;
    ca.X = x; ca.raw = ei; ca.EF = ef;
    ca.tp = tp; ca.wq = wp;
    ca.flags = flags;
    ca.deg = deg; ca.bsum = bsum; ca.row_ptr = row_ptr; ca.cursor = cursor;
    ca.srcs = srcs; ca.eids = eids;
    ca.xbf = xbf; ca.efg = efg;
    void* kargs[] = { &ca };
    hipError_t cerr = hipLaunchCooperativeKernel(
        reinterpret_cast<void*>(coop_prep), dim3(COOPG), dim3(256), kargs, 0, stream);
    if (cerr != hipSuccess) {
        hipLaunchKernelGGL(detect_fmt, dim3(1), dim3(64), 0, stream, (const u32*)x, ei, flags);
        (void)hipMemsetAsync(deg, 0, (size_t)N * 4, stream);
        hipLaunchKernelGGL(convert_count, dim3(CXB + CDB), dim3(256), 0, stream,
                           x, ei, flags, xbf, deg, N * 128, E);
        hipLaunchKernelGGL(prep_w, dim3(32 + 202), dim3(256), 0, stream, tp, wp, flags);
        hipLaunchKernelGGL(scan_a, dim3(NB196), dim3(256), 0, stream, deg, bsum, N);
        hipLaunchKernelGGL(scan_b, dim3(1), dim3(256), 0, stream, bsum, NB196);
        hipLaunchKernelGGL(scan_c, dim3(NB196), dim3(256), 0, stream, deg, bsum, row_ptr,
                           cursor, N);
        hipLaunchKernelGGL(fill_csr, dim3((E + 255) / 256), dim3(256), 0, stream, ei, flags,
                           cursor, srcs, eids, E);
        hipLaunchKernelGGL(gather_ef, dim3(E * 4 / 256), dim3(256), 0, stream,
                           eids, ef, flags, efg, E);
    }

    const int gN = (N + 63) / 64;    // 782
    const int gA = (N + 3) / 4;      // 12500 (1 node per wave)

    // layer 1: q,k,v,sk + qWe (two halves); q & qwe pre-scaled by s2_1
    {
        GemmSets S;
        S.Wt[0] = WtQ1; S.bias[0] = bq1;  S.O[0] = q;        S.bf32[0] = 0; S.pitch[0] = 128; S.oscale[0] = s2_1;
        S.Wt[1] = WtK1; S.bias[1] = bk1;  S.O[1] = kv;       S.bf32[1] = 0; S.pitch[1] = 256; S.oscale[1] = 1.f;
        S.Wt[2] = WtV1; S.bias[2] = bv1;  S.O[2] = kv + 128; S.bf32[2] = 0; S.pitch[2] = 256; S.oscale[2] = 1.f;
        S.Wt[3] = WtS1; S.bias[3] = bs1;  S.O[3] = sk;       S.bf32[3] = 0; S.pitch[3] = 128; S.oscale[3] = 1.f;
        S.Wt[4] = WtqA; S.bias[4] = bqe1;       S.O[4] = qweA; S.bf32[4] = 1; S.pitch[4] = 128; S.oscale[4] = s2_1;
        S.Wt[5] = WtqB; S.bias[5] = bqe1 + 128; S.O[5] = qweB; S.bf32[5] = 1; S.pitch[5] = 128; S.oscale[5] = s2_1;
        hipLaunchKernelGGL(gemm128, dim3(gN, 6), dim3(256), 0, stream, xbf, flags, S, N);
    }
    hipLaunchKernelGGL((attn_kernel<8, 0>), dim3(gA), dim3(256), 0, stream,
                       row_ptr, srcs, q, kv, efg, qweA, qweB, sk, WeP1, (void*)h, N);

    // layer 2: q,k,v,sk + qWe2; q & qwe2 pre-scaled by s2_2 (x0.125 in wqe)
    {
        GemmSets S;
        S.Wt[0] = WtQ2; S.bias[0] = bq2;  S.O[0] = q;        S.bf32[0] = 0; S.pitch[0] = 128; S.oscale[0] = s2_2;
        S.Wt[1] = WtK2; S.bias[1] = bk2;  S.O[1] = kv;       S.bf32[1] = 0; S.pitch[1] = 256; S.oscale[1] = 1.f;
        S.Wt[2] = WtV2; S.bias[2] = bv2;  S.O[2] = kv + 128; S.bf32[2] = 0; S.pitch[2] = 256; S.oscale[2] = 1.f;
        S.Wt[3] = WtS2; S.bias[3] = bs2;  S.O[3] = sk;       S.bf32[3] = 0; S.pitch[3] = 128; S.oscale[3] = 1.f;
        S.Wt[4] = Wtq2; S.bias[4] = bqe2; S.O[4] = qwe2;     S.bf32[4] = 1; S.pitch[4] = 128; S.oscale[4] = s2_2;
        S.Wt[5] = Wtq2; S.bias[5] = bqe2; S.O[5] = qwe2;     S.bf32[5] = 1; S.pitch[5] = 128; S.oscale[5] = s2_2;
        hipLaunchKernelGGL(gemm128, dim3(gN, 5), dim3(256), 0, stream, h, flags, S, N);
    }
    hipLaunchKernelGGL((attn_kernel<1, 1>), dim3(gA), dim3(256), 0, stream,
                       row_ptr, srcs, q, kv, efg, qwe2, qwe2, sk, WeP2, d_out, N);
}

// Round 8
// 430.951 us; speedup vs baseline: 2.4877x; 2.4877x over previous
//
#include <hip/hip_runtime.h>

// GraphAttentionEmbedding: 2x TransformerConv (PyG) on MI355X (gfx950).
// N=50000, E=400000, IN=128, H1=8*16=128, OUT=128, EDIM=32.
// PROVEN: fp32 inputs (runtime-detected), fp32 output; internal bf16+fp32 acc.
// R17-R21 lessons: attn pinned ~59us across occ 30-49% / MLP 24-48 loads ->
// keep R18's proven attn. Cooperative mega-kernel = disaster (720us; grid.sync
// cost + too little MLP at 512 blocks) -> multi-launch prep stays.
// R22: revert to R18 structure + merged-set GEMM: one block stages the A-tile
// ONCE and loops over all weight sets (B is L2-hot 32KB/set) -> A-fetch /6
// (~77MB -> ~13MB per layer). Everything else identical to R18 (429.8us).

using u16 = unsigned short;
using u32 = unsigned int;

#define NODES 50000
#define EDGES 400000
#define NB196 196   // ceil(50000/256)

typedef __attribute__((ext_vector_type(8))) short bf16x8;
typedef __attribute__((ext_vector_type(4))) float f32x4;

__device__ __forceinline__ float bflo(u32 u) { return __uint_as_float(u << 16); }
__device__ __forceinline__ float bfhi(u32 u) { return __uint_as_float(u & 0xffff0000u); }
__device__ __forceinline__ u16 f2bf(float f) {
    u32 u = __float_as_uint(f);
    u += 0x7fffu + ((u >> 16) & 1u);   // RNE
    return (u16)(u >> 16);
}
__device__ __forceinline__ u32 pack2(float a, float b) {
    return (u32)f2bf(a) | ((u32)f2bf(b) << 16);
}
__device__ __forceinline__ float rdv(const void* p, int i, int f) {
    return f ? ((const float*)p)[i]
             : __uint_as_float(((u32) reinterpret_cast<const u16*>(p)[i]) << 16);
}

// dot2 on packed bf16 pairs: p = a.lo*b.lo + a.hi*b.hi + c
#if __has_builtin(__builtin_amdgcn_fdot2_f32_bf16)
typedef __attribute__((ext_vector_type(2))) __bf16 bf2;
__device__ __forceinline__ float dot2bf(u32 a, u32 b, float c) {
    return __builtin_amdgcn_fdot2_f32_bf16(__builtin_bit_cast(bf2, a),
                                           __builtin_bit_cast(bf2, b), c, false);
}
#else
__device__ __forceinline__ float dot2bf(u32 a, u32 b, float c) {
    return fmaf(bflo(a), bflo(b), fmaf(bfhi(a), bfhi(b), c));
}
#endif

__device__ __forceinline__ float fexp2(float x) {
#if __has_builtin(__builtin_amdgcn_exp2f)
    return __builtin_amdgcn_exp2f(x);
#else
    return exp2f(x);
#endif
}

// DPP lane-add at VALU speed (no DS pipe).
template <int CTRL>
__device__ __forceinline__ float dpp_addf(float x) {
    int y = __builtin_amdgcn_update_dpp(0, __float_as_int(x), CTRL, 0xF, 0xF, true);
    return x + __int_as_float(y);
}
template <int GRP>
__device__ __forceinline__ float grp_sum(float p, int lane) {
    p = dpp_addf<0xB1>(p);    // xor 1
    p = dpp_addf<0x4E>(p);    // xor 2
    p = dpp_addf<0x141>(p);   // xor 4 (8-group done)
    if (GRP == 64) {
        p = dpp_addf<0x140>(p);   // xor 8
        p += __int_as_float(__builtin_amdgcn_ds_swizzle(__float_as_int(p), 0x401F)); // xor16
        p += __int_as_float(__builtin_amdgcn_ds_bpermute((lane ^ 32) << 2,
                                                         __float_as_int(p)));        // xor32
    }
    return p;
}

// Broadcast lane ((lane&0x18)|SRC)'s u32 to its 8-lane group (BitMode swizzle).
template <int SRC>
__device__ __forceinline__ u32 bcast8u(u32 x) {
    return (u32)__builtin_amdgcn_ds_swizzle((int)x, 0x18 | (SRC << 5));
}

// ---------------- diagnostic sentinel (fp32 out) ----------------------------
__global__ __launch_bounds__(256) void fill_sentinel(float* __restrict__ out, int n, float val) {
    int i = blockIdx.x * 256 + threadIdx.x;
    if (i < n) out[i] = val;
}

// ---------------- runtime format detection (one wave) -----------------------
__global__ __launch_bounds__(64) void detect_fmt(const u32* __restrict__ xw,
                                                 const int* __restrict__ eraw,
                                                 int* __restrict__ flags) {
    int lane = threadIdx.x;
    u32 e = (xw[lane] >> 7) & 0xffu;
    unsigned long long sane = __ballot(e >= 90u && e <= 141u);
    unsigned long long zodd = __ballot(eraw[1 + 2 * lane] == 0);
    if (lane == 0) {
        flags[0] = (sane == ~0ull) ? 0 : 1;   // 1 = fp32
        flags[1] = (zodd == ~0ull) ? 1 : 0;   // 1 = int64
    }
}

// ---------------- merged: x->bf16 convert (blocks [0,CXB)) + deg count ------
#define CXB 3125    // 50000*128/8/256
#define CDB 1563    // ceil(400000/256)
__global__ __launch_bounds__(256) void convert_count(
    const void* __restrict__ X, const int* __restrict__ raw,
    const int* __restrict__ flags, u16* __restrict__ xbf,
    int* __restrict__ deg, int total, int E) {
    int b = blockIdx.x;
    if (b < CXB) {
        int i = (b * 256 + threadIdx.x) * 8;
        if (i >= total) return;
        if (flags[0]) {
            const float* xf = (const float*)X + i;
            float4 lo = *reinterpret_cast<const float4*>(xf);
            float4 hi = *reinterpret_cast<const float4*>(xf + 4);
            uint4 val = make_uint4(pack2(lo.x, lo.y), pack2(lo.z, lo.w),
                                   pack2(hi.x, hi.y), pack2(hi.z, hi.w));
            *reinterpret_cast<uint4*>(xbf + i) = val;
        } else {
            *reinterpret_cast<uint4*>(xbf + i) =
                *reinterpret_cast<const uint4*>((const u16*)X + i);
        }
    } else {
        int e = (b - CXB) * 256 + threadIdx.x;
        if (e < E) {
            int f = flags[1];
            int d = f ? raw[2 * (E + e)] : raw[E + e];
            if ((unsigned)d < (unsigned)NODES) atomicAdd(&deg[d], 1);
        }
    }
}

// ---------------- weight prep: transpose (blocks [0,32)) + wqe + WeP --------
struct TPtrs {
    const void* src[8];
    u16*        dst[8];
    int         K[8];
};
struct WqeP {
    const void *Wq1, *We1, *bq1, *Wq2, *We2, *bq2;
    u16 *WtA, *WtB, *Wt2;
    float *bqe1, *bqe2;
    uint2 *WeP1, *WeP2;
};

__device__ __forceinline__ void wqe_item(const WqeP& Q, int idx, int f) {
    if (idx < 32768) {                          // layer-1 combined weights
        int col = idx >> 7, i = idx & 127;
        int hh = col >> 5, d = col & 31;
        float s = 0.f;
#pragma unroll
        for (int c = 0; c < 16; ++c)
            s += rdv(Q.Wq1, i * 128 + hh * 16 + c, f) * rdv(Q.We1, d * 128 + hh * 16 + c, f);
        if (col < 128) Q.WtA[col * 128 + i] = f2bf(s);
        else           Q.WtB[(col - 128) * 128 + i] = f2bf(s);
    } else if (idx < 49152) {                   // layer-2 weights (zero-padded, x0.125)
        int t = idx - 32768;
        int col = t >> 7, i = t & 127;
        float s = 0.f;
        if (col < 32) {
            for (int c = 0; c < 128; ++c)
                s += rdv(Q.Wq2, i * 128 + c, f) * rdv(Q.We2, col * 128 + c, f);
        }
        Q.Wt2[col * 128 + i] = f2bf(s * 0.125f);
    } else if (idx < 49408) {                   // bqe1
        int col = idx - 49152;
        int hh = col >> 5, d = col & 31;
        float s = 0.f;
#pragma unroll
        for (int c = 0; c < 16; ++c)
            s += rdv(Q.bq1, hh * 16 + c, f) * rdv(Q.We1, d * 128 + hh * 16 + c, f);
        Q.bqe1[col] = s;
    } else if (idx < 49536) {                   // bqe2 (x0.125)
        int d = idx - 49408;
        float s = 0.f;
        if (d < 32)
            for (int c = 0; c < 128; ++c)
                s += rdv(Q.bq2, c, f) * rdv(Q.We2, d * 128 + c, f);
        Q.bqe2[d] = s * 0.125f;
    } else if (idx < 50560) {                   // WeP1: 1024 entries
        int ent = idx - 49536;
        int t = ent >> 6, l = ent & 63, c0 = 2 * l;
        u32 xv = pack2(rdv(Q.We1, (2 * t) * 128 + c0, f),
                       rdv(Q.We1, (2 * t + 1) * 128 + c0, f));
        u32 yv = pack2(rdv(Q.We1, (2 * t) * 128 + c0 + 1, f),
                       rdv(Q.We1, (2 * t + 1) * 128 + c0 + 1, f));
        Q.WeP1[ent] = make_uint2(xv, yv);
    } else if (idx < 51584) {                   // WeP2: 1024 entries
        int ent = idx - 50560;
        int t = ent >> 6, l = ent & 63, c0 = 2 * l;
        u32 xv = pack2(rdv(Q.We2, (2 * t) * 128 + c0, f),
                       rdv(Q.We2, (2 * t + 1) * 128 + c0, f));
        u32 yv = pack2(rdv(Q.We2, (2 * t) * 128 + c0 + 1, f),
                       rdv(Q.We2, (2 * t + 1) * 128 + c0 + 1, f));
        Q.WeP2[ent] = make_uint2(xv, yv);
    }
}

__global__ __launch_bounds__(256) void prep_w(TPtrs P, WqeP Q, const int* __restrict__ flags) {
    int f = flags[0];
    int b = blockIdx.x;
    if (b < 32) {
        int m = b >> 2;
        int quarter = 16384 >> 2;
        u16* d = P.dst[m];
        int base = (b & 3) * quarter;
        const float* sf = (const float*)P.src[m];
        const u16*   sb = (const u16*)P.src[m];
        for (int idx = base + threadIdx.x; idx < base + quarter; idx += 256) {
            int k = idx >> 7, n = idx & 127;
            d[n * 128 + k] = f ? f2bf(sf[idx]) : sb[idx];
        }
        return;
    }
    int idx = (b - 32) * 256 + threadIdx.x;
    if (idx < 51584) wqe_item(Q, idx, f);
}

// ---------------- CSR build (by dst) ----------------------------------------
__device__ __forceinline__ int block_scan256(int v) {
    __shared__ int ws[4];
    int t = threadIdx.x, lane = t & 63, w = t >> 6;
    int x = v;
#pragma unroll
    for (int off = 1; off < 64; off <<= 1) {
        int y = __shfl_up(x, off, 64);
        if (lane >= off) x += y;
    }
    if (lane == 63) ws[w] = x;
    __syncthreads();
#pragma unroll
    for (int j = 0; j < 3; ++j)
        if (j < w) x += ws[j];
    return x;
}

__global__ __launch_bounds__(256) void scan_a(const int* __restrict__ deg,
                                              int* __restrict__ bsum, int n) {
    int i = blockIdx.x * 256 + threadIdx.x;
    int v = (i < n) ? deg[i] : 0;
    int incl = block_scan256(v);
    if (threadIdx.x == 255) bsum[blockIdx.x] = incl;
}

__global__ __launch_bounds__(256) void scan_b(int* __restrict__ bsum, int nb) {
    int t = threadIdx.x;
    int v = (t < nb) ? bsum[t] : 0;
    int incl = block_scan256(v);
    if (t < nb) bsum[t] = incl - v;
}

__global__ __launch_bounds__(256) void scan_c(const int* __restrict__ deg,
                                              const int* __restrict__ bsum,
                                              int* __restrict__ row_ptr,
                                              int* __restrict__ cursor, int n) {
    int b = blockIdx.x;
    int i = b * 256 + threadIdx.x;
    int v = (i < n) ? deg[i] : 0;
    int incl = block_scan256(v) + bsum[b];
    if (i < n) {
        row_ptr[i + 1] = incl;
        cursor[i] = incl - v;
    }
    if (i == 0) row_ptr[0] = 0;
}

__global__ __launch_bounds__(256) void fill_csr(const int* __restrict__ raw,
                                                const int* __restrict__ flags,
                                                int* __restrict__ cursor,
                                                int* __restrict__ srcs,
                                                int* __restrict__ eids, int E) {
    int e = blockIdx.x * 256 + threadIdx.x;
    if (e < E) {
        int f = flags[1];
        int d = f ? raw[2 * (E + e)] : raw[E + e];
        int s = f ? raw[2 * e] : raw[e];
        if ((unsigned)d < (unsigned)NODES && (unsigned)s < (unsigned)NODES) {
            int pos = atomicAdd(&cursor[d], 1);
            if ((unsigned)pos < (unsigned)E) { srcs[pos] = s; eids[pos] = e; }
        }
    }
}

// ---------------- ef gather to CSR order, bf16 (shared by both layers) ------
__global__ __launch_bounds__(256) void gather_ef(const int* __restrict__ eids,
                                                 const void* __restrict__ EF,
                                                 const int* __restrict__ flags,
                                                 u16* __restrict__ EFG, int E) {
    int t = blockIdx.x * 256 + threadIdx.x;
    int pos = t >> 2, seg = t & 3;
    if (pos >= E) return;
    int e = eids[pos];
    uint4 val;
    if (flags[0]) {
        const float* src = (const float*)EF + (size_t)e * 32 + seg * 8;
        float4 lo = *reinterpret_cast<const float4*>(src);
        float4 hi = *reinterpret_cast<const float4*>(src + 4);
        val = make_uint4(pack2(lo.x, lo.y), pack2(lo.z, lo.w),
                         pack2(hi.x, hi.y), pack2(hi.z, hi.w));
    } else {
        val = *reinterpret_cast<const uint4*>((const u16*)EF + (size_t)e * 32 + seg * 8);
    }
    *reinterpret_cast<uint4*>(EFG + (size_t)pos * 32 + seg * 8) = val;
}

// ---------------- merged-set GEMM: stage A once, loop weight sets -----------
// O_s[M,128] = (A[M,128] @ Wt_s^T + bias_s) * oscale_s  for s in [0,nsets).
// One block owns a 64-row A-tile (staged once from HBM); per set, B (32KB,
// L2-hot: every block reads the same 6 sets) is staged and 64 MFMAs issued.
// A-fetch per layer: 77MB (grid.y=6 form) -> ~13MB.
struct GemmSets {
    const u16*  Wt[6];
    const void* bias[6];
    u16*        O[6];
    int         bf32[6];    // 1 = bias is fp32 always, 0 = follow input flags
    int         pitch[6];   // output row pitch in u16 elements
    float       oscale[6];  // output scale (1.0 for k/v/sk)
};

__global__ __launch_bounds__(256) void gemm128m(
    const u16* __restrict__ A, const int* __restrict__ flags, GemmSets S,
    int nsets, int M) {
    constexpr int K = 128;
    constexpr int PAD = K + 8;
    constexpr int KV = K / 8;
    __shared__ u16 Asl[64 * PAD];
    __shared__ u16 Bsl[128 * PAD];

    int fin = flags[0];
    int m0 = blockIdx.x * 64;

    for (int idx = threadIdx.x; idx < 64 * KV; idx += 256) {
        int r = idx / KV, cv = idx % KV;
        int gr = m0 + r;
        uint4 val = make_uint4(0, 0, 0, 0);
        if (gr < M) val = *reinterpret_cast<const uint4*>(A + (size_t)gr * K + cv * 8);
        *reinterpret_cast<uint4*>(&Asl[r * PAD + cv * 8]) = val;
    }

    int lane = threadIdx.x & 63, wv = threadIdx.x >> 6;
    int l15 = lane & 15;
    int quad = lane >> 4;
    int kq = quad * 8;
    int row = m0 + wv * 16 + l15;

    for (int si = 0; si < nsets; ++si) {
        const u16*  Wt   = S.Wt[si];
        const void* bias = S.bias[si];
        u16*        O    = S.O[si];
        int   pitch = S.pitch[si];
        float os    = S.oscale[si];
        int   f     = S.bf32[si] ? 1 : fin;

        __syncthreads();   // prev compute done (and A staged, first iter)
        for (int idx = threadIdx.x; idx < 128 * KV; idx += 256) {
            int r = idx / KV, cv = idx % KV;
            *reinterpret_cast<uint4*>(&Bsl[r * PAD + cv * 8]) =
                *reinterpret_cast<const uint4*>(Wt + r * K + cv * 8);
        }
        __syncthreads();

        f32x4 b4[8];
#pragma unroll
        for (int nt = 0; nt < 8; ++nt) {
            int col0 = nt * 16 + quad * 4;
            if (bias) {
                if (f) {
                    b4[nt] = *reinterpret_cast<const f32x4*>((const float*)bias + col0);
                } else {
                    uint2 bu = *reinterpret_cast<const uint2*>((const u16*)bias + col0);
                    b4[nt][0] = bflo(bu.x); b4[nt][1] = bfhi(bu.x);
                    b4[nt][2] = bflo(bu.y); b4[nt][3] = bfhi(bu.y);
                }
            } else {
                b4[nt][0] = b4[nt][1] = b4[nt][2] = b4[nt][3] = 0.f;
            }
        }

        f32x4 acc[8] = {};
#pragma unroll
        for (int k0 = 0; k0 < K; k0 += 32) {
            bf16x8 xf = *reinterpret_cast<const bf16x8*>(&Asl[(wv * 16 + l15) * PAD + k0 + kq]);
#pragma unroll
            for (int nt = 0; nt < 8; ++nt) {
                bf16x8 wf = *reinterpret_cast<const bf16x8*>(&Bsl[(nt * 16 + l15) * PAD + k0 + kq]);
                acc[nt] = __builtin_amdgcn_mfma_f32_16x16x32_bf16(wf, xf, acc[nt], 0, 0, 0);
            }
        }

        if (row < M) {
            u16* Orow = O + (size_t)row * pitch;
#pragma unroll
            for (int nt = 0; nt < 8; ++nt) {
                uint2 pk;
                pk.x = pack2((acc[nt][0] + b4[nt][0]) * os, (acc[nt][1] + b4[nt][1]) * os);
                pk.y = pack2((acc[nt][2] + b4[nt][2]) * os, (acc[nt][3] + b4[nt][3]) * os);
                *reinterpret_cast<uint2*>(Orow + nt * 16 + quad * 4) = pk;
            }
        }
    }
}

// ---------------- attention: R18 proven form (59.4us, VGPR 40) --------------
// Per wave = one dst node. Lane (h=lane>>3, j=lane&7) owns channels 16h+2j..+1
// and ef dims 4j..4j+3. Score p = q.k + qw.ef (scale pre-folded via gemm
// oscale) -> w = exp2(p). Exact-8 main loop + masked-4 tail. Epilogue: F
// packed bf16, bcast8 per group, dot2 vs WeP (loaded post-loop).
template <int HEADS, int F32OUT>
__global__ __launch_bounds__(256) void attn_kernel(
    const int* __restrict__ row_ptr, const int* __restrict__ srcs,
    const u16* __restrict__ Q, const u16* __restrict__ KV,
    const u16* __restrict__ EFG,
    const u16* __restrict__ QWA, const u16* __restrict__ QWB,
    const u16* __restrict__ SK, const uint2* __restrict__ WeP,
    void* __restrict__ OUT, int nn) {
    int wv = threadIdx.x >> 6, lane = threadIdx.x & 63;
    int node = blockIdx.x * 4 + wv;
    if (node >= nn) return;
    int h = lane >> 3, j = lane & 7;
    int c0 = lane * 2;
    constexpr int GRP = (HEADS == 8) ? 8 : 64;

    u32 qb = *reinterpret_cast<const u32*>(Q + (size_t)node * 128 + c0);
    const u16* qp = (HEADS == 8)
        ? ((h < 4 ? QWA : QWB) + (size_t)node * 128 + (h & 3) * 32 + j * 4)
        : (QWA + (size_t)node * 128 + j * 4);
    uint2 qwu = *reinterpret_cast<const uint2*>(qp);

    int beg = __builtin_amdgcn_readfirstlane(row_ptr[node]);
    int end = __builtin_amdgcn_readfirstlane(row_ptr[node + 1]);

    float l_run = 0.f, a0 = 0.f, a1 = 0.f;
    float f0 = 0.f, f1 = 0.f, f2 = 0.f, f3 = 0.f;

    auto edge_step = [&](u32 kbv, u32 vbv, uint2 ebv, bool valid) {
        float p = dot2bf(qb, kbv,
                 dot2bf(qwu.x, ebv.x,
                 dot2bf(qwu.y, ebv.y, 0.f)));
        p = grp_sum<GRP>(p, lane);
        float w = fexp2(p);
        if (!valid) w = 0.f;
        l_run += w;
        a0 = fmaf(w, bflo(vbv), a0);
        a1 = fmaf(w, bfhi(vbv), a1);
        f0 = fmaf(w, bflo(ebv.x), f0); f1 = fmaf(w, bfhi(ebv.x), f1);
        f2 = fmaf(w, bflo(ebv.y), f2); f3 = fmaf(w, bfhi(ebv.y), f3);
    };

    int i = beg;
    for (; i + 8 <= end; i += 8) {          // exact batches, no masking
        u32 kb[8], vb[8]; uint2 eb[8];
#pragma unroll
        for (int t = 0; t < 8; ++t) {
            int s = srcs[i + t];            // uniform -> s_load
            const u16* kp = KV + (size_t)s * 256;
            kb[t] = *reinterpret_cast<const u32*>(kp + c0);
            vb[t] = *reinterpret_cast<const u32*>(kp + 128 + c0);
            eb[t] = *reinterpret_cast<const uint2*>(EFG + (size_t)(i + t) * 32 + j * 4);
        }
#pragma unroll
        for (int t = 0; t < 8; ++t) edge_step(kb[t], vb[t], eb[t], true);
    }
    for (; i < end; i += 4) {               // masked tail, batch 4
        int kleft = end - i;
        u32 kb[4], vb[4]; uint2 eb[4];
#pragma unroll
        for (int t = 0; t < 4; ++t) {
            int idx = (i + t < end) ? i + t : end - 1;
            int s = srcs[idx];
            const u16* kp = KV + (size_t)s * 256;
            kb[t] = *reinterpret_cast<const u32*>(kp + c0);
            vb[t] = *reinterpret_cast<const u32*>(kp + 128 + c0);
            eb[t] = *reinterpret_cast<const uint2*>(EFG + (size_t)idx * 32 + j * 4);
        }
#pragma unroll
        for (int t = 0; t < 4; ++t) edge_step(kb[t], vb[t], eb[t], t < kleft);
    }

    // ---- epilogue: out_ee[c] = sum_d F[d]*We[d][c], packed F + dot2 --------
    u32 Fp0 = pack2(f0, f1), Fp1 = pack2(f2, f3);
    float acc0 = 0.f, acc1 = 0.f;
#define EPI(SRC) do { \
        u32 A = bcast8u<SRC>(Fp0), B = bcast8u<SRC>(Fp1); \
        uint2 w0 = WeP[(2 * SRC) * 64 + lane]; \
        uint2 w1 = WeP[(2 * SRC + 1) * 64 + lane]; \
        acc0 = dot2bf(A, w0.x, acc0); acc0 = dot2bf(B, w1.x, acc0); \
        acc1 = dot2bf(A, w0.y, acc1); acc1 = dot2bf(B, w1.y, acc1); \
    } while (0)
    EPI(0); EPI(1); EPI(2); EPI(3); EPI(4); EPI(5); EPI(6); EPI(7);
#undef EPI

    float inv = 1.f / fmaxf(l_run, 1e-16f);
    u32 sb = *reinterpret_cast<const u32*>(SK + (size_t)node * 128 + c0);
    float o0 = fmaxf(fmaf(a0 + acc0, inv, bflo(sb)), 0.f);
    float o1 = fmaxf(fmaf(a1 + acc1, inv, bfhi(sb)), 0.f);
    if (F32OUT) {
        *reinterpret_cast<float2*>((float*)OUT + (size_t)node * 128 + c0) =
            make_float2(o0, o1);
    } else {
        *reinterpret_cast<u32*>((u16*)OUT + (size_t)node * 128 + c0) = pack2(o0, o1);
    }
}

// ---------------------------------------------------------------------------
extern "C" void kernel_launch(void* const* d_in, const int* in_sizes, int n_in,
                              void* d_out, int out_size, void* d_ws, size_t ws_size,
                              hipStream_t stream) {
    const int N = NODES, E = EDGES;
    const void* x  = d_in[0];
    const int*  ei = (const int*)d_in[1];
    const void* ef = d_in[2];
    const void* Wq1 = d_in[3];  const void* bq1 = d_in[4];
    const void* Wk1 = d_in[5];  const void* bk1 = d_in[6];
    const void* Wv1 = d_in[7];  const void* bv1 = d_in[8];
    const void* We1 = d_in[9];
    const void* Ws1 = d_in[10]; const void* bs1 = d_in[11];
    const void* Wq2 = d_in[12]; const void* bq2 = d_in[13];
    const void* Wk2 = d_in[14]; const void* bk2 = d_in[15];
    const void* Wv2 = d_in[16]; const void* bv2 = d_in[17];
    const void* We2 = d_in[18];
    const void* Ws2 = d_in[19]; const void* bs2 = d_in[20];

    char* ws = (char*)d_ws;
    size_t off = 0;
    auto carve = [&](size_t bytes) -> void* {
        void* p = ws + off;
        off += (bytes + 255) & ~(size_t)255;
        return p;
    };

    u16* WtQ1 = (u16*)carve(128 * 128 * 2);
    u16* WtK1 = (u16*)carve(128 * 128 * 2);
    u16* WtV1 = (u16*)carve(128 * 128 * 2);
    u16* WtS1 = (u16*)carve(128 * 128 * 2);
    u16* WtQ2 = (u16*)carve(128 * 128 * 2);
    u16* WtK2 = (u16*)carve(128 * 128 * 2);
    u16* WtV2 = (u16*)carve(128 * 128 * 2);
    u16* WtS2 = (u16*)carve(128 * 128 * 2);
    u16* WtqA = (u16*)carve(128 * 128 * 2);
    u16* WtqB = (u16*)carve(128 * 128 * 2);
    u16* Wtq2 = (u16*)carve(128 * 128 * 2);
    float* bqe1 = (float*)carve(256 * 4);
    float* bqe2 = (float*)carve(128 * 4);
    uint2* WeP1 = (uint2*)carve(1024 * 8);
    uint2* WeP2 = (uint2*)carve(1024 * 8);
    int* flags   = (int*)carve(256);
    int* deg     = (int*)carve((size_t)N * 4);
    int* bsum    = (int*)carve((size_t)NB196 * 4);
    int* row_ptr = (int*)carve((size_t)(N + 1) * 4);
    int* cursor  = (int*)carve((size_t)N * 4);
    int* srcs    = (int*)carve((size_t)E * 4);
    int* eids    = (int*)carve((size_t)E * 4);
    u16* xbf  = (u16*)carve((size_t)N * 128 * 2);
    u16* q    = (u16*)carve((size_t)N * 128 * 2);
    u16* kv   = (u16*)carve((size_t)N * 256 * 2);   // k rows [0:128], v rows [128:256]
    u16* sk   = (u16*)carve((size_t)N * 128 * 2);
    u16* h    = (u16*)carve((size_t)N * 128 * 2);
    u16* qweA = (u16*)carve((size_t)N * 128 * 2);
    u16* qweB = (u16*)carve((size_t)N * 128 * 2);
    u16* qwe2 = (u16*)carve((size_t)N * 128 * 2);
    u16* efg  = (u16*)carve((size_t)E * 32 * 2);
    const size_t REQ = off;   // ~146 MB

    if (ws_size < REQ) {
        hipLaunchKernelGGL(fill_sentinel, dim3((out_size + 255) / 256), dim3(256), 0, stream,
                           (float*)d_out, out_size, 16.0f * (float)(ws_size >> 20));
        return;
    }

    const float s2_1 = 0.25f * 1.44269504f;               // 1/sqrt(16) * log2(e)
    const float s2_2 = 0.08838834764831845f * 1.44269504f; // 1/sqrt(128) * log2(e)

    hipLaunchKernelGGL(detect_fmt, dim3(1), dim3(64), 0, stream, (const u32*)x, ei, flags);

    (void)hipMemsetAsync(deg, 0, (size_t)N * 4, stream);
    hipLaunchKernelGGL(convert_count, dim3(CXB + CDB), dim3(256), 0, stream,
                       x, ei, flags, xbf, deg, N * 128, E);

    TPtrs tp;
    tp.src[0] = Wq1; tp.dst[0] = WtQ1; tp.K[0] = 128;
    tp.src[1] = Wk1; tp.dst[1] = WtK1; tp.K[1] = 128;
    tp.src[2] = Wv1; tp.dst[2] = WtV1; tp.K[2] = 128;
    tp.src[3] = Ws1; tp.dst[3] = WtS1; tp.K[3] = 128;
    tp.src[4] = Wq2; tp.dst[4] = WtQ2; tp.K[4] = 128;
    tp.src[5] = Wk2; tp.dst[5] = WtK2; tp.K[5] = 128;
    tp.src[6] = Wv2; tp.dst[6] = WtV2; tp.K[6] = 128;
    tp.src[7] = Ws2; tp.dst[7] = WtS2; tp.K[7] = 128;
    WqeP wp;
    wp.Wq1 = Wq1; wp.We1 = We1; wp.bq1 = bq1;
    wp.Wq2 = Wq2; wp.We2 = We2; wp.bq2 = bq2;
    wp.WtA = WtqA; wp.WtB = WtqB; wp.Wt2 = Wtq2;
    wp.bqe1 = bqe1; wp.bqe2 = bqe2;
    wp.WeP1 = WeP1; wp.WeP2 = WeP2;
    hipLaunchKernelGGL(prep_w, dim3(32 + 202), dim3(256), 0, stream, tp, wp, flags);

    hipLaunchKernelGGL(scan_a, dim3(NB196), dim3(256), 0, stream, deg, bsum, N);
    hipLaunchKernelGGL(scan_b, dim3(1), dim3(256), 0, stream, bsum, NB196);
    hipLaunchKernelGGL(scan_c, dim3(NB196), dim3(256), 0, stream, deg, bsum, row_ptr, cursor, N);
    hipLaunchKernelGGL(fill_csr, dim3((E + 255) / 256), dim3(256), 0, stream, ei, flags, cursor,
                       srcs, eids, E);

    hipLaunchKernelGGL(gather_ef, dim3(E * 4 / 256), dim3(256), 0, stream,
                       eids, ef, flags, efg, E);

    const int gN = (N + 63) / 64;    // 782
    const int gA = (N + 3) / 4;      // 12500 (1 node per wave)

    // layer 1: q,k,v,sk + qWe (two halves); q & qwe pre-scaled by s2_1
    {
        GemmSets S;
        S.Wt[0] = WtQ1; S.bias[0] = bq1;  S.O[0] = q;        S.bf32[0] = 0; S.pitch[0] = 128; S.oscale[0] = s2_1;
        S.Wt[1] = WtK1; S.bias[1] = bk1;  S.O[1] = kv;       S.bf32[1] = 0; S.pitch[1] = 256; S.oscale[1] = 1.f;
        S.Wt[2] = WtV1; S.bias[2] = bv1;  S.O[2] = kv + 128; S.bf32[2] = 0; S.pitch[2] = 256; S.oscale[2] = 1.f;
        S.Wt[3] = WtS1; S.bias[3] = bs1;  S.O[3] = sk;       S.bf32[3] = 0; S.pitch[3] = 128; S.oscale[3] = 1.f;
        S.Wt[4] = WtqA; S.bias[4] = bqe1;       S.O[4] = qweA; S.bf32[4] = 1; S.pitch[4] = 128; S.oscale[4] = s2_1;
        S.Wt[5] = WtqB; S.bias[5] = bqe1 + 128; S.O[5] = qweB; S.bf32[5] = 1; S.pitch[5] = 128; S.oscale[5] = s2_1;
        hipLaunchKernelGGL(gemm128m, dim3(gN), dim3(256), 0, stream, xbf, flags, S, 6, N);
    }
    hipLaunchKernelGGL((attn_kernel<8, 0>), dim3(gA), dim3(256), 0, stream,
                       row_ptr, srcs, q, kv, efg, qweA, qweB, sk, WeP1, (void*)h, N);

    // layer 2: q,k,v,sk + qWe2; q & qwe2 pre-scaled by s2_2 (x0.125 in wqe)
    {
        GemmSets S;
        S.Wt[0] = WtQ2; S.bias[0] = bq2;  S.O[0] = q;        S.bf32[0] = 0; S.pitch[0] = 128; S.oscale[0] = s2_2;
        S.Wt[1] = WtK2; S.bias[1] = bk2;  S.O[1] = kv;       S.bf32[1] = 0; S.pitch[1] = 256; S.oscale[1] = 1.f;
        S.Wt[2] = WtV2; S.bias[2] = bv2;  S.O[2] = kv + 128; S.bf32[2] = 0; S.pitch[2] = 256; S.oscale[2] = 1.f;
        S.Wt[3] = WtS2; S.bias[3] = bs2;  S.O[3] = sk;       S.bf32[3] = 0; S.pitch[3] = 128; S.oscale[3] = 1.f;
        S.Wt[4] = Wtq2; S.bias[4] = bqe2; S.O[4] = qwe2;     S.bf32[4] = 1; S.pitch[4] = 128; S.oscale[4] = s2_2;
        S.Wt[5] = Wtq2; S.bias[5] = bqe2; S.O[5] = qwe2;     S.bf32[5] = 1; S.pitch[5] = 128; S.oscale[5] = s2_2;
        hipLaunchKernelGGL(gemm128m, dim3(gN), dim3(256), 0, stream, h, flags, S, 5, N);
    }
    hipLaunchKernelGGL((attn_kernel<1, 1>), dim3(gA), dim3(256), 0, stream,
                       row_ptr, srcs, q, kv, efg, qwe2, qwe2, sk, WeP2, d_out, N);
}

// Round 9
// 429.819 us; speedup vs baseline: 2.4942x; 1.0026x over previous
//
#include <hip/hip_runtime.h>

// GraphAttentionEmbedding: 2x TransformerConv (PyG) on MI355X (gfx950).
// N=50000, E=400000, IN=128, H1=8*16=128, OUT=128, EDIM=32.
// PROVEN: fp32 inputs (runtime-detected), fp32 output; internal bf16+fp32 acc.
// R17-R22 lessons: attn pinned ~59us (structural); gemm not A-fetch-bound
// (R22 merged-set gemm = no change); every non-attn kernel < 59us -> non-attn
// 312us = many mid kernels + ~6us/dispatch serialization.
// R23: pipeline compaction, 13 -> 9 dispatches:
//   - inline wave-ballot format detection (detect_fmt dispatch gone)
//   - mega1 = convert_x + count_deg + prep_w (one dispatch, writes flags)
//   - scan_bc = scan_b+scan_c merged (each block re-scans 196-entry bsum)
//   - fill_gather = fill_csr + ef->efg gather fused: ef[e] read is SEQUENTIAL,
//     eids array + gather_ef pass (~77MB) eliminated
//   - gemm128m + attn byte-identical to R22 (proven).

using u16 = unsigned short;
using u32 = unsigned int;

#define NODES 50000
#define EDGES 400000
#define NB196 196   // ceil(50000/256)

typedef __attribute__((ext_vector_type(8))) short bf16x8;
typedef __attribute__((ext_vector_type(4))) float f32x4;

__device__ __forceinline__ float bflo(u32 u) { return __uint_as_float(u << 16); }
__device__ __forceinline__ float bfhi(u32 u) { return __uint_as_float(u & 0xffff0000u); }
__device__ __forceinline__ u16 f2bf(float f) {
    u32 u = __float_as_uint(f);
    u += 0x7fffu + ((u >> 16) & 1u);   // RNE
    return (u16)(u >> 16);
}
__device__ __forceinline__ u32 pack2(float a, float b) {
    return (u32)f2bf(a) | ((u32)f2bf(b) << 16);
}
__device__ __forceinline__ float rdv(const void* p, int i, int f) {
    return f ? ((const float*)p)[i]
             : __uint_as_float(((u32) reinterpret_cast<const u16*>(p)[i]) << 16);
}

// Wave-ballot runtime format detection (all 64 lanes must be active).
__device__ __forceinline__ void detect_inline(const u32* __restrict__ xw,
                                              const int* __restrict__ eraw,
                                              int& f, int& f1) {
    int lane = threadIdx.x & 63;
    u32 e = (xw[lane] >> 7) & 0xffu;
    unsigned long long sane = __ballot(e >= 90u && e <= 141u);
    unsigned long long zodd = __ballot(eraw[1 + 2 * lane] == 0);
    f  = (sane == ~0ull) ? 0 : 1;   // 1 = fp32
    f1 = (zodd == ~0ull) ? 1 : 0;   // 1 = int64
}

// dot2 on packed bf16 pairs: p = a.lo*b.lo + a.hi*b.hi + c
#if __has_builtin(__builtin_amdgcn_fdot2_f32_bf16)
typedef __attribute__((ext_vector_type(2))) __bf16 bf2;
__device__ __forceinline__ float dot2bf(u32 a, u32 b, float c) {
    return __builtin_amdgcn_fdot2_f32_bf16(__builtin_bit_cast(bf2, a),
                                           __builtin_bit_cast(bf2, b), c, false);
}
#else
__device__ __forceinline__ float dot2bf(u32 a, u32 b, float c) {
    return fmaf(bflo(a), bflo(b), fmaf(bfhi(a), bfhi(b), c));
}
#endif

__device__ __forceinline__ float fexp2(float x) {
#if __has_builtin(__builtin_amdgcn_exp2f)
    return __builtin_amdgcn_exp2f(x);
#else
    return exp2f(x);
#endif
}

// DPP lane-add at VALU speed (no DS pipe).
template <int CTRL>
__device__ __forceinline__ float dpp_addf(float x) {
    int y = __builtin_amdgcn_update_dpp(0, __float_as_int(x), CTRL, 0xF, 0xF, true);
    return x + __int_as_float(y);
}
template <int GRP>
__device__ __forceinline__ float grp_sum(float p, int lane) {
    p = dpp_addf<0xB1>(p);    // xor 1
    p = dpp_addf<0x4E>(p);    // xor 2
    p = dpp_addf<0x141>(p);   // xor 4 (8-group done)
    if (GRP == 64) {
        p = dpp_addf<0x140>(p);   // xor 8
        p += __int_as_float(__builtin_amdgcn_ds_swizzle(__float_as_int(p), 0x401F)); // xor16
        p += __int_as_float(__builtin_amdgcn_ds_bpermute((lane ^ 32) << 2,
                                                         __float_as_int(p)));        // xor32
    }
    return p;
}

// Broadcast lane ((lane&0x18)|SRC)'s u32 to its 8-lane group (BitMode swizzle).
template <int SRC>
__device__ __forceinline__ u32 bcast8u(u32 x) {
    return (u32)__builtin_amdgcn_ds_swizzle((int)x, 0x18 | (SRC << 5));
}

// ---------------- diagnostic sentinel (fp32 out) ----------------------------
__global__ __launch_bounds__(256) void fill_sentinel(float* __restrict__ out, int n, float val) {
    int i = blockIdx.x * 256 + threadIdx.x;
    if (i < n) out[i] = val;
}

// ---------------- weight prep structs ---------------------------------------
struct TPtrs {
    const void* src[8];
    u16*        dst[8];
    int         K[8];
};
struct WqeP {
    const void *Wq1, *We1, *bq1, *Wq2, *We2, *bq2;
    u16 *WtA, *WtB, *Wt2;
    float *bqe1, *bqe2;
    uint2 *WeP1, *WeP2;
};

__device__ __forceinline__ void wqe_item(const WqeP& Q, int idx, int f) {
    if (idx < 32768) {                          // layer-1 combined weights
        int col = idx >> 7, i = idx & 127;
        int hh = col >> 5, d = col & 31;
        float s = 0.f;
#pragma unroll
        for (int c = 0; c < 16; ++c)
            s += rdv(Q.Wq1, i * 128 + hh * 16 + c, f) * rdv(Q.We1, d * 128 + hh * 16 + c, f);
        if (col < 128) Q.WtA[col * 128 + i] = f2bf(s);
        else           Q.WtB[(col - 128) * 128 + i] = f2bf(s);
    } else if (idx < 49152) {                   // layer-2 weights (zero-padded, x0.125)
        int t = idx - 32768;
        int col = t >> 7, i = t & 127;
        float s = 0.f;
        if (col < 32) {
            for (int c = 0; c < 128; ++c)
                s += rdv(Q.Wq2, i * 128 + c, f) * rdv(Q.We2, col * 128 + c, f);
        }
        Q.Wt2[col * 128 + i] = f2bf(s * 0.125f);
    } else if (idx < 49408) {                   // bqe1
        int col = idx - 49152;
        int hh = col >> 5, d = col & 31;
        float s = 0.f;
#pragma unroll
        for (int c = 0; c < 16; ++c)
            s += rdv(Q.bq1, hh * 16 + c, f) * rdv(Q.We1, d * 128 + hh * 16 + c, f);
        Q.bqe1[col] = s;
    } else if (idx < 49536) {                   // bqe2 (x0.125)
        int d = idx - 49408;
        float s = 0.f;
        if (d < 32)
            for (int c = 0; c < 128; ++c)
                s += rdv(Q.bq2, c, f) * rdv(Q.We2, d * 128 + c, f);
        Q.bqe2[d] = s * 0.125f;
    } else if (idx < 50560) {                   // WeP1: 1024 entries
        int ent = idx - 49536;
        int t = ent >> 6, l = ent & 63, c0 = 2 * l;
        u32 xv = pack2(rdv(Q.We1, (2 * t) * 128 + c0, f),
                       rdv(Q.We1, (2 * t + 1) * 128 + c0, f));
        u32 yv = pack2(rdv(Q.We1, (2 * t) * 128 + c0 + 1, f),
                       rdv(Q.We1, (2 * t + 1) * 128 + c0 + 1, f));
        Q.WeP1[ent] = make_uint2(xv, yv);
    } else if (idx < 51584) {                   // WeP2: 1024 entries
        int ent = idx - 50560;
        int t = ent >> 6, l = ent & 63, c0 = 2 * l;
        u32 xv = pack2(rdv(Q.We2, (2 * t) * 128 + c0, f),
                       rdv(Q.We2, (2 * t + 1) * 128 + c0, f));
        u32 yv = pack2(rdv(Q.We2, (2 * t) * 128 + c0 + 1, f),
                       rdv(Q.We2, (2 * t + 1) * 128 + c0 + 1, f));
        Q.WeP2[ent] = make_uint2(xv, yv);
    }
}

// ---------------- mega1: convert x + count deg + all weight prep ------------
// blocks [0,CXB): x->bf16 convert; [CXB,CXB+CDB): deg count;
// [CXB+CDB, +32): weight transpose; rest: wqe/WeP items.
// Format detected inline per wave; block 0 publishes flags for gemm.
#define CXB 3125    // 50000*128/8/256
#define CDB 1563    // ceil(400000/256)
#define MGB (CXB + CDB + 32 + 202)
__global__ __launch_bounds__(256) void mega1(
    const void* __restrict__ X, const int* __restrict__ raw,
    TPtrs P, WqeP Q, u16* __restrict__ xbf, int* __restrict__ deg,
    int* __restrict__ flags, int total, int E) {
    int f, f1;
    detect_inline((const u32*)X, raw, f, f1);
    int b = blockIdx.x;
    if (b == 0 && threadIdx.x == 0) { flags[0] = f; flags[1] = f1; }

    if (b < CXB) {
        int i = (b * 256 + threadIdx.x) * 8;
        if (i >= total) return;
        if (f) {
            const float* xf = (const float*)X + i;
            float4 lo = *reinterpret_cast<const float4*>(xf);
            float4 hi = *reinterpret_cast<const float4*>(xf + 4);
            *reinterpret_cast<uint4*>(xbf + i) =
                make_uint4(pack2(lo.x, lo.y), pack2(lo.z, lo.w),
                           pack2(hi.x, hi.y), pack2(hi.z, hi.w));
        } else {
            *reinterpret_cast<uint4*>(xbf + i) =
                *reinterpret_cast<const uint4*>((const u16*)X + i);
        }
    } else if (b < CXB + CDB) {
        int e = (b - CXB) * 256 + threadIdx.x;
        if (e < E) {
            int d = f1 ? raw[2 * (E + e)] : raw[E + e];
            if ((unsigned)d < (unsigned)NODES) atomicAdd(&deg[d], 1);
        }
    } else {
        int bb = b - CXB - CDB;
        if (bb < 32) {
            int m = bb >> 2;
            int quarter = 16384 >> 2;
            u16* d = P.dst[m];
            int base = (bb & 3) * quarter;
            const float* sf = (const float*)P.src[m];
            const u16*   sb = (const u16*)P.src[m];
            for (int idx = base + threadIdx.x; idx < base + quarter; idx += 256) {
                int k = idx >> 7, n = idx & 127;
                d[n * 128 + k] = f ? f2bf(sf[idx]) : sb[idx];
            }
        } else {
            int idx = (bb - 32) * 256 + threadIdx.x;
            if (idx < 51584) wqe_item(Q, idx, f);
        }
    }
}

// ---------------- CSR build (by dst) ----------------------------------------
__device__ __forceinline__ int block_scan256(int v) {
    __shared__ int ws[4];
    int t = threadIdx.x, lane = t & 63, w = t >> 6;
    int x = v;
#pragma unroll
    for (int off = 1; off < 64; off <<= 1) {
        int y = __shfl_up(x, off, 64);
        if (lane >= off) x += y;
    }
    if (lane == 63) ws[w] = x;
    __syncthreads();
#pragma unroll
    for (int j = 0; j < 3; ++j)
        if (j < w) x += ws[j];
    return x;
}

__global__ __launch_bounds__(256) void scan_a(const int* __restrict__ deg,
                                              int* __restrict__ bsum, int n) {
    int i = blockIdx.x * 256 + threadIdx.x;
    int v = (i < n) ? deg[i] : 0;
    int incl = block_scan256(v);
    if (threadIdx.x == 255) bsum[blockIdx.x] = incl;
}

// scan_b + scan_c merged: every block re-scans the 196-entry bsum (L2-hot)
// to get its own chunk base, then scans its deg chunk -> row_ptr + cursor.
__global__ __launch_bounds__(256) void scan_bc(const int* __restrict__ deg,
                                               const int* __restrict__ bsum,
                                               int* __restrict__ row_ptr,
                                               int* __restrict__ cursor, int n) {
    __shared__ int sb[256];
    int c = blockIdx.x;
    int t = threadIdx.x;
    int v0 = (t < NB196) ? bsum[t] : 0;
    int incl0 = block_scan256(v0);
    sb[t] = incl0;
    __syncthreads();                       // also fences ws[] reuse
    int base = (c > 0) ? sb[c - 1] : 0;
    int i = c * 256 + t;
    int v = (i < n) ? deg[i] : 0;
    int incl = block_scan256(v) + base;
    if (i < n) {
        row_ptr[i + 1] = incl;
        cursor[i] = incl - v;
    }
    if (i == 0) row_ptr[0] = 0;
}

// ---------------- fill CSR + fused ef gather (eids pass eliminated) ---------
// Edge e (sequential): pos = cursor[dst]++; srcs[pos]=src; efg[pos] = bf16(ef[e]).
// ef read is SEQUENTIAL (e = thread id); scattered 64B bf16 write to efg[pos].
__global__ __launch_bounds__(256) void fill_gather(
    const int* __restrict__ raw, const u32* __restrict__ xw,
    const void* __restrict__ EF, int* __restrict__ cursor,
    int* __restrict__ srcs, u16* __restrict__ EFG, int E) {
    int f, f1;
    detect_inline(xw, raw, f, f1);
    int e = blockIdx.x * 256 + threadIdx.x;
    if (e >= E) return;
    int d = f1 ? raw[2 * (E + e)] : raw[E + e];
    int s = f1 ? raw[2 * e] : raw[e];
    if ((unsigned)d < (unsigned)NODES && (unsigned)s < (unsigned)NODES) {
        int pos = atomicAdd(&cursor[d], 1);
        if ((unsigned)pos < (unsigned)E) {
            srcs[pos] = s;
            u16* dst = EFG + (size_t)pos * 32;
            if (f) {
                const float* src = (const float*)EF + (size_t)e * 32;
#pragma unroll
                for (int seg = 0; seg < 4; ++seg) {
                    float4 lo = *reinterpret_cast<const float4*>(src + seg * 8);
                    float4 hi = *reinterpret_cast<const float4*>(src + seg * 8 + 4);
                    *reinterpret_cast<uint4*>(dst + seg * 8) =
                        make_uint4(pack2(lo.x, lo.y), pack2(lo.z, lo.w),
                                   pack2(hi.x, hi.y), pack2(hi.z, hi.w));
                }
            } else {
                const uint4* src =
                    reinterpret_cast<const uint4*>((const u16*)EF + (size_t)e * 32);
#pragma unroll
                for (int seg = 0; seg < 4; ++seg)
                    *reinterpret_cast<uint4*>(dst + seg * 8) = src[seg];
            }
        }
    }
}

// ---------------- merged-set GEMM: stage A once, loop weight sets -----------
struct GemmSets {
    const u16*  Wt[6];
    const void* bias[6];
    u16*        O[6];
    int         bf32[6];    // 1 = bias is fp32 always, 0 = follow input flags
    int         pitch[6];   // output row pitch in u16 elements
    float       oscale[6];  // output scale (1.0 for k/v/sk)
};

__global__ __launch_bounds__(256) void gemm128m(
    const u16* __restrict__ A, const int* __restrict__ flags, GemmSets S,
    int nsets, int M) {
    constexpr int K = 128;
    constexpr int PAD = K + 8;
    constexpr int KV = K / 8;
    __shared__ u16 Asl[64 * PAD];
    __shared__ u16 Bsl[128 * PAD];

    int fin = flags[0];
    int m0 = blockIdx.x * 64;

    for (int idx = threadIdx.x; idx < 64 * KV; idx += 256) {
        int r = idx / KV, cv = idx % KV;
        int gr = m0 + r;
        uint4 val = make_uint4(0, 0, 0, 0);
        if (gr < M) val = *reinterpret_cast<const uint4*>(A + (size_t)gr * K + cv * 8);
        *reinterpret_cast<uint4*>(&Asl[r * PAD + cv * 8]) = val;
    }

    int lane = threadIdx.x & 63, wv = threadIdx.x >> 6;
    int l15 = lane & 15;
    int quad = lane >> 4;
    int kq = quad * 8;
    int row = m0 + wv * 16 + l15;

    for (int si = 0; si < nsets; ++si) {
        const u16*  Wt   = S.Wt[si];
        const void* bias = S.bias[si];
        u16*        O    = S.O[si];
        int   pitch = S.pitch[si];
        float os    = S.oscale[si];
        int   f     = S.bf32[si] ? 1 : fin;

        __syncthreads();   // prev compute done (and A staged, first iter)
        for (int idx = threadIdx.x; idx < 128 * KV; idx += 256) {
            int r = idx / KV, cv = idx % KV;
            *reinterpret_cast<uint4*>(&Bsl[r * PAD + cv * 8]) =
                *reinterpret_cast<const uint4*>(Wt + r * K + cv * 8);
        }
        __syncthreads();

        f32x4 b4[8];
#pragma unroll
        for (int nt = 0; nt < 8; ++nt) {
            int col0 = nt * 16 + quad * 4;
            if (bias) {
                if (f) {
                    b4[nt] = *reinterpret_cast<const f32x4*>((const float*)bias + col0);
                } else {
                    uint2 bu = *reinterpret_cast<const uint2*>((const u16*)bias + col0);
                    b4[nt][0] = bflo(bu.x); b4[nt][1] = bfhi(bu.x);
                    b4[nt][2] = bflo(bu.y); b4[nt][3] = bfhi(bu.y);
                }
            } else {
                b4[nt][0] = b4[nt][1] = b4[nt][2] = b4[nt][3] = 0.f;
            }
        }

        f32x4 acc[8] = {};
#pragma unroll
        for (int k0 = 0; k0 < K; k0 += 32) {
            bf16x8 xf = *reinterpret_cast<const bf16x8*>(&Asl[(wv * 16 + l15) * PAD + k0 + kq]);
#pragma unroll
            for (int nt = 0; nt < 8; ++nt) {
                bf16x8 wf = *reinterpret_cast<const bf16x8*>(&Bsl[(nt * 16 + l15) * PAD + k0 + kq]);
                acc[nt] = __builtin_amdgcn_mfma_f32_16x16x32_bf16(wf, xf, acc[nt], 0, 0, 0);
            }
        }

        if (row < M) {
            u16* Orow = O + (size_t)row * pitch;
#pragma unroll
            for (int nt = 0; nt < 8; ++nt) {
                uint2 pk;
                pk.x = pack2((acc[nt][0] + b4[nt][0]) * os, (acc[nt][1] + b4[nt][1]) * os);
                pk.y = pack2((acc[nt][2] + b4[nt][2]) * os, (acc[nt][3] + b4[nt][3]) * os);
                *reinterpret_cast<uint2*>(Orow + nt * 16 + quad * 4) = pk;
            }
        }
    }
}

// ---------------- attention: R18 proven form (59.4us, VGPR 40) --------------
template <int HEADS, int F32OUT>
__global__ __launch_bounds__(256) void attn_kernel(
    const int* __restrict__ row_ptr, const int* __restrict__ srcs,
    const u16* __restrict__ Q, const u16* __restrict__ KV,
    const u16* __restrict__ EFG,
    const u16* __restrict__ QWA, const u16* __restrict__ QWB,
    const u16* __restrict__ SK, const uint2* __restrict__ WeP,
    void* __restrict__ OUT, int nn) {
    int wv = threadIdx.x >> 6, lane = threadIdx.x & 63;
    int node = blockIdx.x * 4 + wv;
    if (node >= nn) return;
    int h = lane >> 3, j = lane & 7;
    int c0 = lane * 2;
    constexpr int GRP = (HEADS == 8) ? 8 : 64;

    u32 qb = *reinterpret_cast<const u32*>(Q + (size_t)node * 128 + c0);
    const u16* qp = (HEADS == 8)
        ? ((h < 4 ? QWA : QWB) + (size_t)node * 128 + (h & 3) * 32 + j * 4)
        : (QWA + (size_t)node * 128 + j * 4);
    uint2 qwu = *reinterpret_cast<const uint2*>(qp);

    int beg = __builtin_amdgcn_readfirstlane(row_ptr[node]);
    int end = __builtin_amdgcn_readfirstlane(row_ptr[node + 1]);

    float l_run = 0.f, a0 = 0.f, a1 = 0.f;
    float f0 = 0.f, f1 = 0.f, f2 = 0.f, f3 = 0.f;

    auto edge_step = [&](u32 kbv, u32 vbv, uint2 ebv, bool valid) {
        float p = dot2bf(qb, kbv,
                 dot2bf(qwu.x, ebv.x,
                 dot2bf(qwu.y, ebv.y, 0.f)));
        p = grp_sum<GRP>(p, lane);
        float w = fexp2(p);
        if (!valid) w = 0.f;
        l_run += w;
        a0 = fmaf(w, bflo(vbv), a0);
        a1 = fmaf(w, bfhi(vbv), a1);
        f0 = fmaf(w, bflo(ebv.x), f0); f1 = fmaf(w, bfhi(ebv.x), f1);
        f2 = fmaf(w, bflo(ebv.y), f2); f3 = fmaf(w, bfhi(ebv.y), f3);
    };

    int i = beg;
    for (; i + 8 <= end; i += 8) {          // exact batches, no masking
        u32 kb[8], vb[8]; uint2 eb[8];
#pragma unroll
        for (int t = 0; t < 8; ++t) {
            int s = srcs[i + t];            // uniform -> s_load
            const u16* kp = KV + (size_t)s * 256;
            kb[t] = *reinterpret_cast<const u32*>(kp + c0);
            vb[t] = *reinterpret_cast<const u32*>(kp + 128 + c0);
            eb[t] = *reinterpret_cast<const uint2*>(EFG + (size_t)(i + t) * 32 + j * 4);
        }
#pragma unroll
        for (int t = 0; t < 8; ++t) edge_step(kb[t], vb[t], eb[t], true);
    }
    for (; i < end; i += 4) {               // masked tail, batch 4
        int kleft = end - i;
        u32 kb[4], vb[4]; uint2 eb[4];
#pragma unroll
        for (int t = 0; t < 4; ++t) {
            int idx = (i + t < end) ? i + t : end - 1;
            int s = srcs[idx];
            const u16* kp = KV + (size_t)s * 256;
            kb[t] = *reinterpret_cast<const u32*>(kp + c0);
            vb[t] = *reinterpret_cast<const u32*>(kp + 128 + c0);
            eb[t] = *reinterpret_cast<const uint2*>(EFG + (size_t)idx * 32 + j * 4);
        }
#pragma unroll
        for (int t = 0; t < 4; ++t) edge_step(kb[t], vb[t], eb[t], t < kleft);
    }

    // ---- epilogue: out_ee[c] = sum_d F[d]*We[d][c], packed F + dot2 --------
    u32 Fp0 = pack2(f0, f1), Fp1 = pack2(f2, f3);
    float acc0 = 0.f, acc1 = 0.f;
#define EPI(SRC) do { \
        u32 A = bcast8u<SRC>(Fp0), B = bcast8u<SRC>(Fp1); \
        uint2 w0 = WeP[(2 * SRC) * 64 + lane]; \
        uint2 w1 = WeP[(2 * SRC + 1) * 64 + lane]; \
        acc0 = dot2bf(A, w0.x, acc0); acc0 = dot2bf(B, w1.x, acc0); \
        acc1 = dot2bf(A, w0.y, acc1); acc1 = dot2bf(B, w1.y, acc1); \
    } while (0)
    EPI(0); EPI(1); EPI(2); EPI(3); EPI(4); EPI(5); EPI(6); EPI(7);
#undef EPI

    float inv = 1.f / fmaxf(l_run, 1e-16f);
    u32 sb = *reinterpret_cast<const u32*>(SK + (size_t)node * 128 + c0);
    float o0 = fmaxf(fmaf(a0 + acc0, inv, bflo(sb)), 0.f);
    float o1 = fmaxf(fmaf(a1 + acc1, inv, bfhi(sb)), 0.f);
    if (F32OUT) {
        *reinterpret_cast<float2*>((float*)OUT + (size_t)node * 128 + c0) =
            make_float2(o0, o1);
    } else {
        *reinterpret_cast<u32*>((u16*)OUT + (size_t)node * 128 + c0) = pack2(o0, o1);
    }
}

// ---------------------------------------------------------------------------
extern "C" void kernel_launch(void* const* d_in, const int* in_sizes, int n_in,
                              void* d_out, int out_size, void* d_ws, size_t ws_size,
                              hipStream_t stream) {
    const int N = NODES, E = EDGES;
    const void* x  = d_in[0];
    const int*  ei = (const int*)d_in[1];
    const void* ef = d_in[2];
    const void* Wq1 = d_in[3];  const void* bq1 = d_in[4];
    const void* Wk1 = d_in[5];  const void* bk1 = d_in[6];
    const void* Wv1 = d_in[7];  const void* bv1 = d_in[8];
    const void* We1 = d_in[9];
    const void* Ws1 = d_in[10]; const void* bs1 = d_in[11];
    const void* Wq2 = d_in[12]; const void* bq2 = d_in[13];
    const void* Wk2 = d_in[14]; const void* bk2 = d_in[15];
    const void* Wv2 = d_in[16]; const void* bv2 = d_in[17];
    const void* We2 = d_in[18];
    const void* Ws2 = d_in[19]; const void* bs2 = d_in[20];

    char* ws = (char*)d_ws;
    size_t off = 0;
    auto carve = [&](size_t bytes) -> void* {
        void* p = ws + off;
        off += (bytes + 255) & ~(size_t)255;
        return p;
    };

    u16* WtQ1 = (u16*)carve(128 * 128 * 2);
    u16* WtK1 = (u16*)carve(128 * 128 * 2);
    u16* WtV1 = (u16*)carve(128 * 128 * 2);
    u16* WtS1 = (u16*)carve(128 * 128 * 2);
    u16* WtQ2 = (u16*)carve(128 * 128 * 2);
    u16* WtK2 = (u16*)carve(128 * 128 * 2);
    u16* WtV2 = (u16*)carve(128 * 128 * 2);
    u16* WtS2 = (u16*)carve(128 * 128 * 2);
    u16* WtqA = (u16*)carve(128 * 128 * 2);
    u16* WtqB = (u16*)carve(128 * 128 * 2);
    u16* Wtq2 = (u16*)carve(128 * 128 * 2);
    float* bqe1 = (float*)carve(256 * 4);
    float* bqe2 = (float*)carve(128 * 4);
    uint2* WeP1 = (uint2*)carve(1024 * 8);
    uint2* WeP2 = (uint2*)carve(1024 * 8);
    int* flags   = (int*)carve(256);
    int* deg     = (int*)carve((size_t)N * 4);
    int* bsum    = (int*)carve((size_t)NB196 * 4);
    int* row_ptr = (int*)carve((size_t)(N + 1) * 4);
    int* cursor  = (int*)carve((size_t)N * 4);
    int* srcs    = (int*)carve((size_t)E * 4);
    u16* xbf  = (u16*)carve((size_t)N * 128 * 2);
    u16* q    = (u16*)carve((size_t)N * 128 * 2);
    u16* kv   = (u16*)carve((size_t)N * 256 * 2);   // k rows [0:128], v rows [128:256]
    u16* sk   = (u16*)carve((size_t)N * 128 * 2);
    u16* h    = (u16*)carve((size_t)N * 128 * 2);
    u16* qweA = (u16*)carve((size_t)N * 128 * 2);
    u16* qweB = (u16*)carve((size_t)N * 128 * 2);
    u16* qwe2 = (u16*)carve((size_t)N * 128 * 2);
    u16* efg  = (u16*)carve((size_t)E * 32 * 2);
    const size_t REQ = off;   // ~144 MB

    if (ws_size < REQ) {
        hipLaunchKernelGGL(fill_sentinel, dim3((out_size + 255) / 256), dim3(256), 0, stream,
                           (float*)d_out, out_size, 16.0f * (float)(ws_size >> 20));
        return;
    }

    const float s2_1 = 0.25f * 1.44269504f;               // 1/sqrt(16) * log2(e)
    const float s2_2 = 0.08838834764831845f * 1.44269504f; // 1/sqrt(128) * log2(e)

    TPtrs tp;
    tp.src[0] = Wq1; tp.dst[0] = WtQ1; tp.K[0] = 128;
    tp.src[1] = Wk1; tp.dst[1] = WtK1; tp.K[1] = 128;
    tp.src[2] = Wv1; tp.dst[2] = WtV1; tp.K[2] = 128;
    tp.src[3] = Ws1; tp.dst[3] = WtS1; tp.K[3] = 128;
    tp.src[4] = Wq2; tp.dst[4] = WtQ2; tp.K[4] = 128;
    tp.src[5] = Wk2; tp.dst[5] = WtK2; tp.K[5] = 128;
    tp.src[6] = Wv2; tp.dst[6] = WtV2; tp.K[6] = 128;
    tp.src[7] = Ws2; tp.dst[7] = WtS2; tp.K[7] = 128;
    WqeP wp;
    wp.Wq1 = Wq1; wp.We1 = We1; wp.bq1 = bq1;
    wp.Wq2 = Wq2; wp.We2 = We2; wp.bq2 = bq2;
    wp.WtA = WtqA; wp.WtB = WtqB; wp.Wt2 = Wtq2;
    wp.bqe1 = bqe1; wp.bqe2 = bqe2;
    wp.WeP1 = WeP1; wp.WeP2 = WeP2;

    (void)hipMemsetAsync(deg, 0, (size_t)N * 4, stream);
    hipLaunchKernelGGL(mega1, dim3(MGB), dim3(256), 0, stream,
                       x, ei, tp, wp, xbf, deg, flags, N * 128, E);
    hipLaunchKernelGGL(scan_a, dim3(NB196), dim3(256), 0, stream, deg, bsum, N);
    hipLaunchKernelGGL(scan_bc, dim3(NB196), dim3(256), 0, stream,
                       deg, bsum, row_ptr, cursor, N);
    hipLaunchKernelGGL(fill_gather, dim3((E + 255) / 256), dim3(256), 0, stream,
                       ei, (const u32*)x, ef, cursor, srcs, efg, E);

    const int gN = (N + 63) / 64;    // 782
    const int gA = (N + 3) / 4;      // 12500 (1 node per wave)

    // layer 1: q,k,v,sk + qWe (two halves); q & qwe pre-scaled by s2_1
    {
        GemmSets S;
        S.Wt[0] = WtQ1; S.bias[0] = bq1;  S.O[0] = q;        S.bf32[0] = 0; S.pitch[0] = 128; S.oscale[0] = s2_1;
        S.Wt[1] = WtK1; S.bias[1] = bk1;  S.O[1] = kv;       S.bf32[1] = 0; S.pitch[1] = 256; S.oscale[1] = 1.f;
        S.Wt[2] = WtV1; S.bias[2] = bv1;  S.O[2] = kv + 128; S.bf32[2] = 0; S.pitch[2] = 256; S.oscale[2] = 1.f;
        S.Wt[3] = WtS1; S.bias[3] = bs1;  S.O[3] = sk;       S.bf32[3] = 0; S.pitch[3] = 128; S.oscale[3] = 1.f;
        S.Wt[4] = WtqA; S.bias[4] = bqe1;       S.O[4] = qweA; S.bf32[4] = 1; S.pitch[4] = 128; S.oscale[4] = s2_1;
        S.Wt[5] = WtqB; S.bias[5] = bqe1 + 128; S.O[5] = qweB; S.bf32[5] = 1; S.pitch[5] = 128; S.oscale[5] = s2_1;
        hipLaunchKernelGGL(gemm128m, dim3(gN), dim3(256), 0, stream, xbf, flags, S, 6, N);
    }
    hipLaunchKernelGGL((attn_kernel<8, 0>), dim3(gA), dim3(256), 0, stream,
                       row_ptr, srcs, q, kv, efg, qweA, qweB, sk, WeP1, (void*)h, N);

    // layer 2: q,k,v,sk + qWe2; q & qwe2 pre-scaled by s2_2 (x0.125 in wqe)
    {
        GemmSets S;
        S.Wt[0] = WtQ2; S.bias[0] = bq2;  S.O[0] = q;        S.bf32[0] = 0; S.pitch[0] = 128; S.oscale[0] = s2_2;
        S.Wt[1] = WtK2; S.bias[1] = bk2;  S.O[1] = kv;       S.bf32[1] = 0; S.pitch[1] = 256; S.oscale[1] = 1.f;
        S.Wt[2] = WtV2; S.bias[2] = bv2;  S.O[2] = kv + 128; S.bf32[2] = 0; S.pitch[2] = 256; S.oscale[2] = 1.f;
        S.Wt[3] = WtS2; S.bias[3] = bs2;  S.O[3] = sk;       S.bf32[3] = 0; S.pitch[3] = 128; S.oscale[3] = 1.f;
        S.Wt[4] = Wtq2; S.bias[4] = bqe2; S.O[4] = qwe2;     S.bf32[4] = 1; S.pitch[4] = 128; S.oscale[4] = s2_2;
        S.Wt[5] = Wtq2; S.bias[5] = bqe2; S.O[5] = qwe2;     S.bf32[5] = 1; S.pitch[5] = 128; S.oscale[5] = s2_2;
        hipLaunchKernelGGL(gemm128m, dim3(gN), dim3(256), 0, stream, h, flags, S, 5, N);
    }
    hipLaunchKernelGGL((attn_kernel<1, 1>), dim3(gA), dim3(256), 0, stream,
                       row_ptr, srcs, q, kv, efg, qwe2, qwe2, sk, WeP2, d_out, N);
}

// Round 10
// 410.404 us; speedup vs baseline: 2.6122x; 1.0473x over previous
//
#include <hip/hip_runtime.h>

// GraphAttentionEmbedding: 2x TransformerConv (PyG) on MI355X (gfx950).
// N=50000, E=400000, IN=128, H1=8*16=128, OUT=128, EDIM=32.
// PROVEN: fp32 inputs (runtime-detected), fp32 output; internal bf16+fp32 acc.
// R17-R23 lessons: attn structurally pinned ~59us; non-attn ~311us is REAL
// kernel time in the mid-size kernels (dispatch compaction + traffic removal
// all neutral; fill_gather's scattered 64B writes offset the removed gather).
// R24: exploit the independent-chain concurrency. fill_gather (needs cursor)
// and gemm L1 (needs xbf/weights) have NO dependency -> fuse into ONE kernel:
// blocks [0,1563) fill CSR + gather ef; blocks [1563,2345) gemm L1.
// Pair duration = max(fill, gemm) instead of sum -> save ~min(fill,gemm).
// attn / gemm128m / mega1 / scans byte-identical to R23.

using u16 = unsigned short;
using u32 = unsigned int;

#define NODES 50000
#define EDGES 400000
#define NB196 196   // ceil(50000/256)

typedef __attribute__((ext_vector_type(8))) short bf16x8;
typedef __attribute__((ext_vector_type(4))) float f32x4;

__device__ __forceinline__ float bflo(u32 u) { return __uint_as_float(u << 16); }
__device__ __forceinline__ float bfhi(u32 u) { return __uint_as_float(u & 0xffff0000u); }
__device__ __forceinline__ u16 f2bf(float f) {
    u32 u = __float_as_uint(f);
    u += 0x7fffu + ((u >> 16) & 1u);   // RNE
    return (u16)(u >> 16);
}
__device__ __forceinline__ u32 pack2(float a, float b) {
    return (u32)f2bf(a) | ((u32)f2bf(b) << 16);
}
__device__ __forceinline__ float rdv(const void* p, int i, int f) {
    return f ? ((const float*)p)[i]
             : __uint_as_float(((u32) reinterpret_cast<const u16*>(p)[i]) << 16);
}

// Wave-ballot runtime format detection (all 64 lanes must be active).
__device__ __forceinline__ void detect_inline(const u32* __restrict__ xw,
                                              const int* __restrict__ eraw,
                                              int& f, int& f1) {
    int lane = threadIdx.x & 63;
    u32 e = (xw[lane] >> 7) & 0xffu;
    unsigned long long sane = __ballot(e >= 90u && e <= 141u);
    unsigned long long zodd = __ballot(eraw[1 + 2 * lane] == 0);
    f  = (sane == ~0ull) ? 0 : 1;   // 1 = fp32
    f1 = (zodd == ~0ull) ? 1 : 0;   // 1 = int64
}

// dot2 on packed bf16 pairs: p = a.lo*b.lo + a.hi*b.hi + c
#if __has_builtin(__builtin_amdgcn_fdot2_f32_bf16)
typedef __attribute__((ext_vector_type(2))) __bf16 bf2;
__device__ __forceinline__ float dot2bf(u32 a, u32 b, float c) {
    return __builtin_amdgcn_fdot2_f32_bf16(__builtin_bit_cast(bf2, a),
                                           __builtin_bit_cast(bf2, b), c, false);
}
#else
__device__ __forceinline__ float dot2bf(u32 a, u32 b, float c) {
    return fmaf(bflo(a), bflo(b), fmaf(bfhi(a), bfhi(b), c));
}
#endif

__device__ __forceinline__ float fexp2(float x) {
#if __has_builtin(__builtin_amdgcn_exp2f)
    return __builtin_amdgcn_exp2f(x);
#else
    return exp2f(x);
#endif
}

// DPP lane-add at VALU speed (no DS pipe).
template <int CTRL>
__device__ __forceinline__ float dpp_addf(float x) {
    int y = __builtin_amdgcn_update_dpp(0, __float_as_int(x), CTRL, 0xF, 0xF, true);
    return x + __int_as_float(y);
}
template <int GRP>
__device__ __forceinline__ float grp_sum(float p, int lane) {
    p = dpp_addf<0xB1>(p);    // xor 1
    p = dpp_addf<0x4E>(p);    // xor 2
    p = dpp_addf<0x141>(p);   // xor 4 (8-group done)
    if (GRP == 64) {
        p = dpp_addf<0x140>(p);   // xor 8
        p += __int_as_float(__builtin_amdgcn_ds_swizzle(__float_as_int(p), 0x401F)); // xor16
        p += __int_as_float(__builtin_amdgcn_ds_bpermute((lane ^ 32) << 2,
                                                         __float_as_int(p)));        // xor32
    }
    return p;
}

// Broadcast lane ((lane&0x18)|SRC)'s u32 to its 8-lane group (BitMode swizzle).
template <int SRC>
__device__ __forceinline__ u32 bcast8u(u32 x) {
    return (u32)__builtin_amdgcn_ds_swizzle((int)x, 0x18 | (SRC << 5));
}

// ---------------- diagnostic sentinel (fp32 out) ----------------------------
__global__ __launch_bounds__(256) void fill_sentinel(float* __restrict__ out, int n, float val) {
    int i = blockIdx.x * 256 + threadIdx.x;
    if (i < n) out[i] = val;
}

// ---------------- weight prep structs ---------------------------------------
struct TPtrs {
    const void* src[8];
    u16*        dst[8];
    int         K[8];
};
struct WqeP {
    const void *Wq1, *We1, *bq1, *Wq2, *We2, *bq2;
    u16 *WtA, *WtB, *Wt2;
    float *bqe1, *bqe2;
    uint2 *WeP1, *WeP2;
};

__device__ __forceinline__ void wqe_item(const WqeP& Q, int idx, int f) {
    if (idx < 32768) {                          // layer-1 combined weights
        int col = idx >> 7, i = idx & 127;
        int hh = col >> 5, d = col & 31;
        float s = 0.f;
#pragma unroll
        for (int c = 0; c < 16; ++c)
            s += rdv(Q.Wq1, i * 128 + hh * 16 + c, f) * rdv(Q.We1, d * 128 + hh * 16 + c, f);
        if (col < 128) Q.WtA[col * 128 + i] = f2bf(s);
        else           Q.WtB[(col - 128) * 128 + i] = f2bf(s);
    } else if (idx < 49152) {                   // layer-2 weights (zero-padded, x0.125)
        int t = idx - 32768;
        int col = t >> 7, i = t & 127;
        float s = 0.f;
        if (col < 32) {
            for (int c = 0; c < 128; ++c)
                s += rdv(Q.Wq2, i * 128 + c, f) * rdv(Q.We2, col * 128 + c, f);
        }
        Q.Wt2[col * 128 + i] = f2bf(s * 0.125f);
    } else if (idx < 49408) {                   // bqe1
        int col = idx - 49152;
        int hh = col >> 5, d = col & 31;
        float s = 0.f;
#pragma unroll
        for (int c = 0; c < 16; ++c)
            s += rdv(Q.bq1, hh * 16 + c, f) * rdv(Q.We1, d * 128 + hh * 16 + c, f);
        Q.bqe1[col] = s;
    } else if (idx < 49536) {                   // bqe2 (x0.125)
        int d = idx - 49408;
        float s = 0.f;
        if (d < 32)
            for (int c = 0; c < 128; ++c)
                s += rdv(Q.bq2, c, f) * rdv(Q.We2, d * 128 + c, f);
        Q.bqe2[d] = s * 0.125f;
    } else if (idx < 50560) {                   // WeP1: 1024 entries
        int ent = idx - 49536;
        int t = ent >> 6, l = ent & 63, c0 = 2 * l;
        u32 xv = pack2(rdv(Q.We1, (2 * t) * 128 + c0, f),
                       rdv(Q.We1, (2 * t + 1) * 128 + c0, f));
        u32 yv = pack2(rdv(Q.We1, (2 * t) * 128 + c0 + 1, f),
                       rdv(Q.We1, (2 * t + 1) * 128 + c0 + 1, f));
        Q.WeP1[ent] = make_uint2(xv, yv);
    } else if (idx < 51584) {                   // WeP2: 1024 entries
        int ent = idx - 50560;
        int t = ent >> 6, l = ent & 63, c0 = 2 * l;
        u32 xv = pack2(rdv(Q.We2, (2 * t) * 128 + c0, f),
                       rdv(Q.We2, (2 * t + 1) * 128 + c0, f));
        u32 yv = pack2(rdv(Q.We2, (2 * t) * 128 + c0 + 1, f),
                       rdv(Q.We2, (2 * t + 1) * 128 + c0 + 1, f));
        Q.WeP2[ent] = make_uint2(xv, yv);
    }
}

// ---------------- mega1: convert x + count deg + all weight prep ------------
#define CXB 3125    // 50000*128/8/256
#define CDB 1563    // ceil(400000/256)
#define MGB (CXB + CDB + 32 + 202)
__global__ __launch_bounds__(256) void mega1(
    const void* __restrict__ X, const int* __restrict__ raw,
    TPtrs P, WqeP Q, u16* __restrict__ xbf, int* __restrict__ deg,
    int* __restrict__ flags, int total, int E) {
    int f, f1;
    detect_inline((const u32*)X, raw, f, f1);
    int b = blockIdx.x;
    if (b == 0 && threadIdx.x == 0) { flags[0] = f; flags[1] = f1; }

    if (b < CXB) {
        int i = (b * 256 + threadIdx.x) * 8;
        if (i >= total) return;
        if (f) {
            const float* xf = (const float*)X + i;
            float4 lo = *reinterpret_cast<const float4*>(xf);
            float4 hi = *reinterpret_cast<const float4*>(xf + 4);
            *reinterpret_cast<uint4*>(xbf + i) =
                make_uint4(pack2(lo.x, lo.y), pack2(lo.z, lo.w),
                           pack2(hi.x, hi.y), pack2(hi.z, hi.w));
        } else {
            *reinterpret_cast<uint4*>(xbf + i) =
                *reinterpret_cast<const uint4*>((const u16*)X + i);
        }
    } else if (b < CXB + CDB) {
        int e = (b - CXB) * 256 + threadIdx.x;
        if (e < E) {
            int d = f1 ? raw[2 * (E + e)] : raw[E + e];
            if ((unsigned)d < (unsigned)NODES) atomicAdd(&deg[d], 1);
        }
    } else {
        int bb = b - CXB - CDB;
        if (bb < 32) {
            int m = bb >> 2;
            int quarter = 16384 >> 2;
            u16* d = P.dst[m];
            int base = (bb & 3) * quarter;
            const float* sf = (const float*)P.src[m];
            const u16*   sb = (const u16*)P.src[m];
            for (int idx = base + threadIdx.x; idx < base + quarter; idx += 256) {
                int k = idx >> 7, n = idx & 127;
                d[n * 128 + k] = f ? f2bf(sf[idx]) : sb[idx];
            }
        } else {
            int idx = (bb - 32) * 256 + threadIdx.x;
            if (idx < 51584) wqe_item(Q, idx, f);
        }
    }
}

// ---------------- CSR build (by dst) ----------------------------------------
__device__ __forceinline__ int block_scan256(int v) {
    __shared__ int ws[4];
    int t = threadIdx.x, lane = t & 63, w = t >> 6;
    int x = v;
#pragma unroll
    for (int off = 1; off < 64; off <<= 1) {
        int y = __shfl_up(x, off, 64);
        if (lane >= off) x += y;
    }
    if (lane == 63) ws[w] = x;
    __syncthreads();
#pragma unroll
    for (int j = 0; j < 3; ++j)
        if (j < w) x += ws[j];
    return x;
}

__global__ __launch_bounds__(256) void scan_a(const int* __restrict__ deg,
                                              int* __restrict__ bsum, int n) {
    int i = blockIdx.x * 256 + threadIdx.x;
    int v = (i < n) ? deg[i] : 0;
    int incl = block_scan256(v);
    if (threadIdx.x == 255) bsum[blockIdx.x] = incl;
}

// scan_b + scan_c merged: every block re-scans the 196-entry bsum (L2-hot)
__global__ __launch_bounds__(256) void scan_bc(const int* __restrict__ deg,
                                               const int* __restrict__ bsum,
                                               int* __restrict__ row_ptr,
                                               int* __restrict__ cursor, int n) {
    __shared__ int sb[256];
    int c = blockIdx.x;
    int t = threadIdx.x;
    int v0 = (t < NB196) ? bsum[t] : 0;
    int incl0 = block_scan256(v0);
    sb[t] = incl0;
    __syncthreads();                       // also fences ws[] reuse
    int base = (c > 0) ? sb[c - 1] : 0;
    int i = c * 256 + t;
    int v = (i < n) ? deg[i] : 0;
    int incl = block_scan256(v) + base;
    if (i < n) {
        row_ptr[i + 1] = incl;
        cursor[i] = incl - v;
    }
    if (i == 0) row_ptr[0] = 0;
}

// ---------------- GEMM sets -------------------------------------------------
struct GemmSets {
    const u16*  Wt[6];
    const void* bias[6];
    u16*        O[6];
    int         bf32[6];    // 1 = bias is fp32 always, 0 = follow input flags
    int         pitch[6];   // output row pitch in u16 elements
    float       oscale[6];  // output scale (1.0 for k/v/sk)
};

// shared gemm body (LDS passed in)
__device__ __forceinline__ void gemm_body(
    const u16* __restrict__ A, int fin, const GemmSets& S, int nsets, int M,
    int gblk, u16* Asl, u16* Bsl) {
    constexpr int K = 128;
    constexpr int PAD = K + 8;
    constexpr int KV = K / 8;
    int m0 = gblk * 64;

    for (int idx = threadIdx.x; idx < 64 * KV; idx += 256) {
        int r = idx / KV, cv = idx % KV;
        int gr = m0 + r;
        uint4 val = make_uint4(0, 0, 0, 0);
        if (gr < M) val = *reinterpret_cast<const uint4*>(A + (size_t)gr * K + cv * 8);
        *reinterpret_cast<uint4*>(&Asl[r * PAD + cv * 8]) = val;
    }

    int lane = threadIdx.x & 63, wv = threadIdx.x >> 6;
    int l15 = lane & 15;
    int quad = lane >> 4;
    int kq = quad * 8;
    int row = m0 + wv * 16 + l15;

    for (int si = 0; si < nsets; ++si) {
        const u16*  Wt   = S.Wt[si];
        const void* bias = S.bias[si];
        u16*        O    = S.O[si];
        int   pitch = S.pitch[si];
        float os    = S.oscale[si];
        int   f     = S.bf32[si] ? 1 : fin;

        __syncthreads();   // prev compute done (and A staged, first iter)
        for (int idx = threadIdx.x; idx < 128 * KV; idx += 256) {
            int r = idx / KV, cv = idx % KV;
            *reinterpret_cast<uint4*>(&Bsl[r * PAD + cv * 8]) =
                *reinterpret_cast<const uint4*>(Wt + r * K + cv * 8);
        }
        __syncthreads();

        f32x4 b4[8];
#pragma unroll
        for (int nt = 0; nt < 8; ++nt) {
            int col0 = nt * 16 + quad * 4;
            if (bias) {
                if (f) {
                    b4[nt] = *reinterpret_cast<const f32x4*>((const float*)bias + col0);
                } else {
                    uint2 bu = *reinterpret_cast<const uint2*>((const u16*)bias + col0);
                    b4[nt][0] = bflo(bu.x); b4[nt][1] = bfhi(bu.x);
                    b4[nt][2] = bflo(bu.y); b4[nt][3] = bfhi(bu.y);
                }
            } else {
                b4[nt][0] = b4[nt][1] = b4[nt][2] = b4[nt][3] = 0.f;
            }
        }

        f32x4 acc[8] = {};
#pragma unroll
        for (int k0 = 0; k0 < K; k0 += 32) {
            bf16x8 xf = *reinterpret_cast<const bf16x8*>(&Asl[(wv * 16 + l15) * PAD + k0 + kq]);
#pragma unroll
            for (int nt = 0; nt < 8; ++nt) {
                bf16x8 wf = *reinterpret_cast<const bf16x8*>(&Bsl[(nt * 16 + l15) * PAD + k0 + kq]);
                acc[nt] = __builtin_amdgcn_mfma_f32_16x16x32_bf16(wf, xf, acc[nt], 0, 0, 0);
            }
        }

        if (row < M) {
            u16* Orow = O + (size_t)row * pitch;
#pragma unroll
            for (int nt = 0; nt < 8; ++nt) {
                uint2 pk;
                pk.x = pack2((acc[nt][0] + b4[nt][0]) * os, (acc[nt][1] + b4[nt][1]) * os);
                pk.y = pack2((acc[nt][2] + b4[nt][2]) * os, (acc[nt][3] + b4[nt][3]) * os);
                *reinterpret_cast<uint2*>(Orow + nt * 16 + quad * 4) = pk;
            }
        }
    }
}

// standalone gemm (layer 2)
__global__ __launch_bounds__(256) void gemm128m(
    const u16* __restrict__ A, const int* __restrict__ flags, GemmSets S,
    int nsets, int M) {
    __shared__ u16 Asl[64 * 136];
    __shared__ u16 Bsl[128 * 136];
    gemm_body(A, flags[0], S, nsets, M, blockIdx.x, Asl, Bsl);
}

// ---------------- fused: fill CSR + ef gather (blocks [0,fillB)) ------------
//                  + gemm L1 (blocks [fillB, fillB+gN)) ----------------------
// Independent chains: fill needs cursor (scan_bc); gemm needs xbf/weights
// (mega1). Fused duration ~= max(fill, gemm) instead of sum.
__global__ __launch_bounds__(256) void fill_gemm(
    const int* __restrict__ raw, const u32* __restrict__ xw,
    const void* __restrict__ EF, int* __restrict__ cursor,
    int* __restrict__ srcs, u16* __restrict__ EFG, int E, int fillB,
    const u16* __restrict__ A, const int* __restrict__ flags, GemmSets S,
    int nsets, int M) {
    __shared__ u16 Asl[64 * 136];
    __shared__ u16 Bsl[128 * 136];

    if (blockIdx.x < fillB) {
        int f, f1;
        detect_inline(xw, raw, f, f1);
        int e = blockIdx.x * 256 + threadIdx.x;
        if (e >= E) return;
        int d = f1 ? raw[2 * (E + e)] : raw[E + e];
        int s = f1 ? raw[2 * e] : raw[e];
        if ((unsigned)d < (unsigned)NODES && (unsigned)s < (unsigned)NODES) {
            int pos = atomicAdd(&cursor[d], 1);
            if ((unsigned)pos < (unsigned)E) {
                srcs[pos] = s;
                u16* dst = EFG + (size_t)pos * 32;
                if (f) {
                    const float* src = (const float*)EF + (size_t)e * 32;
#pragma unroll
                    for (int seg = 0; seg < 4; ++seg) {
                        float4 lo = *reinterpret_cast<const float4*>(src + seg * 8);
                        float4 hi = *reinterpret_cast<const float4*>(src + seg * 8 + 4);
                        *reinterpret_cast<uint4*>(dst + seg * 8) =
                            make_uint4(pack2(lo.x, lo.y), pack2(lo.z, lo.w),
                                       pack2(hi.x, hi.y), pack2(hi.z, hi.w));
                    }
                } else {
                    const uint4* src =
                        reinterpret_cast<const uint4*>((const u16*)EF + (size_t)e * 32);
#pragma unroll
                    for (int seg = 0; seg < 4; ++seg)
                        *reinterpret_cast<uint4*>(dst + seg * 8) = src[seg];
                }
            }
        }
        return;
    }
    gemm_body(A, flags[0], S, nsets, M, blockIdx.x - fillB, Asl, Bsl);
}

// ---------------- attention: R18 proven form (59.4us, VGPR 40) --------------
template <int HEADS, int F32OUT>
__global__ __launch_bounds__(256) void attn_kernel(
    const int* __restrict__ row_ptr, const int* __restrict__ srcs,
    const u16* __restrict__ Q, const u16* __restrict__ KV,
    const u16* __restrict__ EFG,
    const u16* __restrict__ QWA, const u16* __restrict__ QWB,
    const u16* __restrict__ SK, const uint2* __restrict__ WeP,
    void* __restrict__ OUT, int nn) {
    int wv = threadIdx.x >> 6, lane = threadIdx.x & 63;
    int node = blockIdx.x * 4 + wv;
    if (node >= nn) return;
    int h = lane >> 3, j = lane & 7;
    int c0 = lane * 2;
    constexpr int GRP = (HEADS == 8) ? 8 : 64;

    u32 qb = *reinterpret_cast<const u32*>(Q + (size_t)node * 128 + c0);
    const u16* qp = (HEADS == 8)
        ? ((h < 4 ? QWA : QWB) + (size_t)node * 128 + (h & 3) * 32 + j * 4)
        : (QWA + (size_t)node * 128 + j * 4);
    uint2 qwu = *reinterpret_cast<const uint2*>(qp);

    int beg = __builtin_amdgcn_readfirstlane(row_ptr[node]);
    int end = __builtin_amdgcn_readfirstlane(row_ptr[node + 1]);

    float l_run = 0.f, a0 = 0.f, a1 = 0.f;
    float f0 = 0.f, f1 = 0.f, f2 = 0.f, f3 = 0.f;

    auto edge_step = [&](u32 kbv, u32 vbv, uint2 ebv, bool valid) {
        float p = dot2bf(qb, kbv,
                 dot2bf(qwu.x, ebv.x,
                 dot2bf(qwu.y, ebv.y, 0.f)));
        p = grp_sum<GRP>(p, lane);
        float w = fexp2(p);
        if (!valid) w = 0.f;
        l_run += w;
        a0 = fmaf(w, bflo(vbv), a0);
        a1 = fmaf(w, bfhi(vbv), a1);
        f0 = fmaf(w, bflo(ebv.x), f0); f1 = fmaf(w, bfhi(ebv.x), f1);
        f2 = fmaf(w, bflo(ebv.y), f2); f3 = fmaf(w, bfhi(ebv.y), f3);
    };

    int i = beg;
    for (; i + 8 <= end; i += 8) {          // exact batches, no masking
        u32 kb[8], vb[8]; uint2 eb[8];
#pragma unroll
        for (int t = 0; t < 8; ++t) {
            int s = srcs[i + t];            // uniform -> s_load
            const u16* kp = KV + (size_t)s * 256;
            kb[t] = *reinterpret_cast<const u32*>(kp + c0);
            vb[t] = *reinterpret_cast<const u32*>(kp + 128 + c0);
            eb[t] = *reinterpret_cast<const uint2*>(EFG + (size_t)(i + t) * 32 + j * 4);
        }
#pragma unroll
        for (int t = 0; t < 8; ++t) edge_step(kb[t], vb[t], eb[t], true);
    }
    for (; i < end; i += 4) {               // masked tail, batch 4
        int kleft = end - i;
        u32 kb[4], vb[4]; uint2 eb[4];
#pragma unroll
        for (int t = 0; t < 4; ++t) {
            int idx = (i + t < end) ? i + t : end - 1;
            int s = srcs[idx];
            const u16* kp = KV + (size_t)s * 256;
            kb[t] = *reinterpret_cast<const u32*>(kp + c0);
            vb[t] = *reinterpret_cast<const u32*>(kp + 128 + c0);
            eb[t] = *reinterpret_cast<const uint2*>(EFG + (size_t)idx * 32 + j * 4);
        }
#pragma unroll
        for (int t = 0; t < 4; ++t) edge_step(kb[t], vb[t], eb[t], t < kleft);
    }

    // ---- epilogue: out_ee[c] = sum_d F[d]*We[d][c], packed F + dot2 --------
    u32 Fp0 = pack2(f0, f1), Fp1 = pack2(f2, f3);
    float acc0 = 0.f, acc1 = 0.f;
#define EPI(SRC) do { \
        u32 A = bcast8u<SRC>(Fp0), B = bcast8u<SRC>(Fp1); \
        uint2 w0 = WeP[(2 * SRC) * 64 + lane]; \
        uint2 w1 = WeP[(2 * SRC + 1) * 64 + lane]; \
        acc0 = dot2bf(A, w0.x, acc0); acc0 = dot2bf(B, w1.x, acc0); \
        acc1 = dot2bf(A, w0.y, acc1); acc1 = dot2bf(B, w1.y, acc1); \
    } while (0)
    EPI(0); EPI(1); EPI(2); EPI(3); EPI(4); EPI(5); EPI(6); EPI(7);
#undef EPI

    float inv = 1.f / fmaxf(l_run, 1e-16f);
    u32 sb = *reinterpret_cast<const u32*>(SK + (size_t)node * 128 + c0);
    float o0 = fmaxf(fmaf(a0 + acc0, inv, bflo(sb)), 0.f);
    float o1 = fmaxf(fmaf(a1 + acc1, inv, bfhi(sb)), 0.f);
    if (F32OUT) {
        *reinterpret_cast<float2*>((float*)OUT + (size_t)node * 128 + c0) =
            make_float2(o0, o1);
    } else {
        *reinterpret_cast<u32*>((u16*)OUT + (size_t)node * 128 + c0) = pack2(o0, o1);
    }
}

// ---------------------------------------------------------------------------
extern "C" void kernel_launch(void* const* d_in, const int* in_sizes, int n_in,
                              void* d_out, int out_size, void* d_ws, size_t ws_size,
                              hipStream_t stream) {
    const int N = NODES, E = EDGES;
    const void* x  = d_in[0];
    const int*  ei = (const int*)d_in[1];
    const void* ef = d_in[2];
    const void* Wq1 = d_in[3];  const void* bq1 = d_in[4];
    const void* Wk1 = d_in[5];  const void* bk1 = d_in[6];
    const void* Wv1 = d_in[7];  const void* bv1 = d_in[8];
    const void* We1 = d_in[9];
    const void* Ws1 = d_in[10]; const void* bs1 = d_in[11];
    const void* Wq2 = d_in[12]; const void* bq2 = d_in[13];
    const void* Wk2 = d_in[14]; const void* bk2 = d_in[15];
    const void* Wv2 = d_in[16]; const void* bv2 = d_in[17];
    const void* We2 = d_in[18];
    const void* Ws2 = d_in[19]; const void* bs2 = d_in[20];

    char* ws = (char*)d_ws;
    size_t off = 0;
    auto carve = [&](size_t bytes) -> void* {
        void* p = ws + off;
        off += (bytes + 255) & ~(size_t)255;
        return p;
    };

    u16* WtQ1 = (u16*)carve(128 * 128 * 2);
    u16* WtK1 = (u16*)carve(128 * 128 * 2);
    u16* WtV1 = (u16*)carve(128 * 128 * 2);
    u16* WtS1 = (u16*)carve(128 * 128 * 2);
    u16* WtQ2 = (u16*)carve(128 * 128 * 2);
    u16* WtK2 = (u16*)carve(128 * 128 * 2);
    u16* WtV2 = (u16*)carve(128 * 128 * 2);
    u16* WtS2 = (u16*)carve(128 * 128 * 2);
    u16* WtqA = (u16*)carve(128 * 128 * 2);
    u16* WtqB = (u16*)carve(128 * 128 * 2);
    u16* Wtq2 = (u16*)carve(128 * 128 * 2);
    float* bqe1 = (float*)carve(256 * 4);
    float* bqe2 = (float*)carve(128 * 4);
    uint2* WeP1 = (uint2*)carve(1024 * 8);
    uint2* WeP2 = (uint2*)carve(1024 * 8);
    int* flags   = (int*)carve(256);
    int* deg     = (int*)carve((size_t)N * 4);
    int* bsum    = (int*)carve((size_t)NB196 * 4);
    int* row_ptr = (int*)carve((size_t)(N + 1) * 4);
    int* cursor  = (int*)carve((size_t)N * 4);
    int* srcs    = (int*)carve((size_t)E * 4);
    u16* xbf  = (u16*)carve((size_t)N * 128 * 2);
    u16* q    = (u16*)carve((size_t)N * 128 * 2);
    u16* kv   = (u16*)carve((size_t)N * 256 * 2);   // k rows [0:128], v rows [128:256]
    u16* sk   = (u16*)carve((size_t)N * 128 * 2);
    u16* h    = (u16*)carve((size_t)N * 128 * 2);
    u16* qweA = (u16*)carve((size_t)N * 128 * 2);
    u16* qweB = (u16*)carve((size_t)N * 128 * 2);
    u16* qwe2 = (u16*)carve((size_t)N * 128 * 2);
    u16* efg  = (u16*)carve((size_t)E * 32 * 2);
    const size_t REQ = off;   // ~144 MB

    if (ws_size < REQ) {
        hipLaunchKernelGGL(fill_sentinel, dim3((out_size + 255) / 256), dim3(256), 0, stream,
                           (float*)d_out, out_size, 16.0f * (float)(ws_size >> 20));
        return;
    }

    const float s2_1 = 0.25f * 1.44269504f;               // 1/sqrt(16) * log2(e)
    const float s2_2 = 0.08838834764831845f * 1.44269504f; // 1/sqrt(128) * log2(e)

    TPtrs tp;
    tp.src[0] = Wq1; tp.dst[0] = WtQ1; tp.K[0] = 128;
    tp.src[1] = Wk1; tp.dst[1] = WtK1; tp.K[1] = 128;
    tp.src[2] = Wv1; tp.dst[2] = WtV1; tp.K[2] = 128;
    tp.src[3] = Ws1; tp.dst[3] = WtS1; tp.K[3] = 128;
    tp.src[4] = Wq2; tp.dst[4] = WtQ2; tp.K[4] = 128;
    tp.src[5] = Wk2; tp.dst[5] = WtK2; tp.K[5] = 128;
    tp.src[6] = Wv2; tp.dst[6] = WtV2; tp.K[6] = 128;
    tp.src[7] = Ws2; tp.dst[7] = WtS2; tp.K[7] = 128;
    WqeP wp;
    wp.Wq1 = Wq1; wp.We1 = We1; wp.bq1 = bq1;
    wp.Wq2 = Wq2; wp.We2 = We2; wp.bq2 = bq2;
    wp.WtA = WtqA; wp.WtB = WtqB; wp.Wt2 = Wtq2;
    wp.bqe1 = bqe1; wp.bqe2 = bqe2;
    wp.WeP1 = WeP1; wp.WeP2 = WeP2;

    (void)hipMemsetAsync(deg, 0, (size_t)N * 4, stream);
    hipLaunchKernelGGL(mega1, dim3(MGB), dim3(256), 0, stream,
                       x, ei, tp, wp, xbf, deg, flags, N * 128, E);
    hipLaunchKernelGGL(scan_a, dim3(NB196), dim3(256), 0, stream, deg, bsum, N);
    hipLaunchKernelGGL(scan_bc, dim3(NB196), dim3(256), 0, stream,
                       deg, bsum, row_ptr, cursor, N);

    const int gN = (N + 63) / 64;       // 782
    const int fillB = (E + 255) / 256;  // 1563
    const int gA = (N + 3) / 4;         // 12500 (1 node per wave)

    // fused: fill CSR+gather (independent) || layer-1 gemm (q,k,v,sk,qWe)
    {
        GemmSets S;
        S.Wt[0] = WtQ1; S.bias[0] = bq1;  S.O[0] = q;        S.bf32[0] = 0; S.pitch[0] = 128; S.oscale[0] = s2_1;
        S.Wt[1] = WtK1; S.bias[1] = bk1;  S.O[1] = kv;       S.bf32[1] = 0; S.pitch[1] = 256; S.oscale[1] = 1.f;
        S.Wt[2] = WtV1; S.bias[2] = bv1;  S.O[2] = kv + 128; S.bf32[2] = 0; S.pitch[2] = 256; S.oscale[2] = 1.f;
        S.Wt[3] = WtS1; S.bias[3] = bs1;  S.O[3] = sk;       S.bf32[3] = 0; S.pitch[3] = 128; S.oscale[3] = 1.f;
        S.Wt[4] = WtqA; S.bias[4] = bqe1;       S.O[4] = qweA; S.bf32[4] = 1; S.pitch[4] = 128; S.oscale[4] = s2_1;
        S.Wt[5] = WtqB; S.bias[5] = bqe1 + 128; S.O[5] = qweB; S.bf32[5] = 1; S.pitch[5] = 128; S.oscale[5] = s2_1;
        hipLaunchKernelGGL(fill_gemm, dim3(fillB + gN), dim3(256), 0, stream,
                           ei, (const u32*)x, ef, cursor, srcs, efg, E, fillB,
                           xbf, flags, S, 6, N);
    }
    hipLaunchKernelGGL((attn_kernel<8, 0>), dim3(gA), dim3(256), 0, stream,
                       row_ptr, srcs, q, kv, efg, qweA, qweB, sk, WeP1, (void*)h, N);

    // layer 2: q,k,v,sk + qWe2; q & qwe2 pre-scaled by s2_2 (x0.125 in wqe)
    {
        GemmSets S;
        S.Wt[0] = WtQ2; S.bias[0] = bq2;  S.O[0] = q;        S.bf32[0] = 0; S.pitch[0] = 128; S.oscale[0] = s2_2;
        S.Wt[1] = WtK2; S.bias[1] = bk2;  S.O[1] = kv;       S.bf32[1] = 0; S.pitch[1] = 256; S.oscale[1] = 1.f;
        S.Wt[2] = WtV2; S.bias[2] = bv2;  S.O[2] = kv + 128; S.bf32[2] = 0; S.pitch[2] = 256; S.oscale[2] = 1.f;
        S.Wt[3] = WtS2; S.bias[3] = bs2;  S.O[3] = sk;       S.bf32[3] = 0; S.pitch[3] = 128; S.oscale[3] = 1.f;
        S.Wt[4] = Wtq2; S.bias[4] = bqe2; S.O[4] = qwe2;     S.bf32[4] = 1; S.pitch[4] = 128; S.oscale[4] = s2_2;
        S.Wt[5] = Wtq2; S.bias[5] = bqe2; S.O[5] = qwe2;     S.bf32[5] = 1; S.pitch[5] = 128; S.oscale[5] = s2_2;
        hipLaunchKernelGGL(gemm128m, dim3(gN), dim3(256), 0, stream, h, flags, S, 5, N);
    }
    hipLaunchKernelGGL((attn_kernel<1, 1>), dim3(gA), dim3(256), 0, stream,
                       row_ptr, srcs, q, kv, efg, qwe2, qwe2, sk, WeP2, d_out, N);
}